// Round 6
// baseline (880.445 us; speedup 1.0000x reference)
//
#include <hip/hip_runtime.h>
#include <hip/hip_bf16.h>

#define S_LEN  2048
#define BATCH  2
#define DMODEL 1024
#define NHEAD  16
#define DHEAD  64
#define DFF    4096
#define NTOK   (BATCH * S_LEN)
#define QKVLD  3072   // fused Q|K|V output row stride
#define NSPLIT 4      // attention split-K factor

typedef __attribute__((ext_vector_type(8))) short short8;
typedef __attribute__((ext_vector_type(4))) short short4v;
typedef __attribute__((ext_vector_type(4))) float f32x4;

__device__ __forceinline__ short f2bs(float f) {
  __hip_bfloat16 h = __float2bfloat16(f);
  short s;
  __builtin_memcpy(&s, &h, sizeof(short));
  return s;
}

__device__ __forceinline__ float bs2f(short s) {
  unsigned u = ((unsigned)(unsigned short)s) << 16;
  float f;
  __builtin_memcpy(&f, &u, sizeof(float));
  return f;
}

__device__ __forceinline__ f32x4 mfma16(short8 a, short8 b, f32x4 c) {
  return __builtin_amdgcn_mfma_f32_16x16x32_bf16(a, b, c, 0, 0, 0);
}

// async global->LDS, 16B per lane; LDS dest = wave-uniform base + lane*16
__device__ __forceinline__ void load_lds16(const short* g, short* l) {
  __builtin_amdgcn_global_load_lds(
      (const __attribute__((address_space(1))) void*)g,
      (__attribute__((address_space(3))) void*)l, 16, 0, 0);
}

// ---------------------------------------------------------------------------
// Weight transpose + cast + scale: in f32 [R][C] -> out bf16 [C][R] * scale
// ---------------------------------------------------------------------------
__global__ void transpose_cast(const float* __restrict__ in, short* __restrict__ out,
                               int R, int C, float scale) {
  __shared__ float tile[32][33];
  const int c0 = blockIdx.x * 32, r0 = blockIdx.y * 32;
  const int tx = threadIdx.x, ty = threadIdx.y;  // 32 x 8
#pragma unroll
  for (int i = 0; i < 32; i += 8)
    tile[ty + i][tx] = in[(size_t)(r0 + ty + i) * C + c0 + tx];
  __syncthreads();
#pragma unroll
  for (int i = 0; i < 32; i += 8)
    out[(size_t)(c0 + ty + i) * R + r0 + tx] = f2bs(tile[tx][ty + i] * scale);
}

// ---------------------------------------------------------------------------
// bf16 transpose: in [R][LDin] -> out [C][R], 64x64 tiles
// ---------------------------------------------------------------------------
__global__ __launch_bounds__(256) void transpose_bf16(
    const short* __restrict__ in, short* __restrict__ out, int R, int LDin) {
  __shared__ __attribute__((aligned(16))) short tile[64][72];
  const int c0 = blockIdx.x * 64, r0 = blockIdx.y * 64;
#pragma unroll
  for (int i = 0; i < 2; i++) {
    const int idx = threadIdx.x + 256 * i;
    const int rr = idx >> 3, cc8 = (idx & 7) * 8;
    *(int4*)(&tile[rr][cc8]) = *(const int4*)(in + (size_t)(r0 + rr) * LDin + c0 + cc8);
  }
  __syncthreads();
#pragma unroll
  for (int i = 0; i < 2; i++) {
    const int idx = threadIdx.x + 256 * i;
    const int rr = idx >> 3, cc8 = (idx & 7) * 8;
    short8 v;
#pragma unroll
    for (int j = 0; j < 8; j++) v[j] = tile[cc8 + j][rr];
    *(short8*)(out + (size_t)(c0 + rr) * R + r0 + cc8) = v;
  }
}

// ---------------------------------------------------------------------------
// bqkv: [0,1024)=bq*0.125, [1024,2048)=bk, [2048,3072)=bv
// ---------------------------------------------------------------------------
__global__ void concat_bias(const float* __restrict__ bq, const float* __restrict__ bk,
                            const float* __restrict__ bv, float* __restrict__ bqkv) {
  const int i = blockIdx.x * 256 + threadIdx.x;
  float v;
  if (i < DMODEL) v = bq[i] * 0.125f;
  else if (i < 2 * DMODEL) v = bk[i - DMODEL];
  else v = bv[i - 2 * DMODEL];
  bqkv[i] = v;
}

// ---------------------------------------------------------------------------
// Token prep: qkb = bf16(src+pos), srcb = bf16(src)
// ---------------------------------------------------------------------------
__global__ void prep_tokens(const float* __restrict__ src, const float* __restrict__ pos,
                            short* __restrict__ qkb, short* __restrict__ srcb) {
  const int i = (blockIdx.x * blockDim.x + threadIdx.x) * 4;
  float4 s = *(const float4*)(src + i);
  float4 p = *(const float4*)(pos + i);
  short4v q4 = {f2bs(s.x + p.x), f2bs(s.y + p.y), f2bs(s.z + p.z), f2bs(s.w + p.w)};
  short4v s4 = {f2bs(s.x), f2bs(s.y), f2bs(s.z), f2bs(s.w)};
  *(short4v*)(qkb + i) = q4;
  *(short4v*)(srcb + i) = s4;
}

// ---------------------------------------------------------------------------
// corr f32 -> bf16
// ---------------------------------------------------------------------------
__global__ void prep_corr(const float* __restrict__ corr, short* __restrict__ corrb) {
  const size_t i = ((size_t)blockIdx.x * 256 + threadIdx.x) * 4;
  float4 c = *(const float4*)(corr + i);
  short4v o = {f2bs(c.x), f2bs(c.y), f2bs(c.z), f2bs(c.w)};
  *(short4v*)(corrb + i) = o;
}

// ---------------------------------------------------------------------------
// GEMM 128x128 (m97-style), dual-A: column blocks with col0 < splitcol read
// A0, others A1 (for fused QKV: Q/K from src+pos, V from src).
// ---------------------------------------------------------------------------
template <int RELU, int OUT_BF16>
__global__ __launch_bounds__(256) void gemm_bt(
    const short* __restrict__ A0, const short* __restrict__ A1,
    const short* __restrict__ Bt, const float* __restrict__ bias,
    float* __restrict__ Cf, short* __restrict__ Cb,
    int M, int N, int K, int splitcol) {
  __shared__ __attribute__((aligned(16))) short As[128 * 32];
  __shared__ __attribute__((aligned(16))) short Bs[128 * 32];

  const int tid = threadIdx.x;
  const int wave = tid >> 6, lane = tid & 63;
  const int lm = lane & 15, lq = lane >> 4;
  const int row0 = blockIdx.y * 128, col0 = blockIdx.x * 128;
  const int wr = (wave >> 1) * 64, wc = (wave & 1) * 64;

  const short* A = (col0 < splitcol) ? A0 : A1;
  const short* ag = A + (size_t)(row0 + wave * 32 + (lane >> 2)) * K + (lane & 3) * 8;
  const short* bg = Bt + (size_t)(col0 + wave * 32 + (lane >> 2)) * K + (lane & 3) * 8;
  short* asl = &As[wave * 32 * 32];
  short* bsl = &Bs[wave * 32 * 32];

  f32x4 acc[4][4];
#pragma unroll
  for (int i = 0; i < 4; i++)
#pragma unroll
    for (int j = 0; j < 4; j++) acc[i][j] = (f32x4){0.f, 0.f, 0.f, 0.f};

  for (int k0 = 0; k0 < K; k0 += 32) {
    load_lds16(ag + k0, asl);
    load_lds16(ag + (size_t)16 * K + k0, asl + 16 * 32);
    load_lds16(bg + k0, bsl);
    load_lds16(bg + (size_t)16 * K + k0, bsl + 16 * 32);
    __syncthreads();

    short8 af[4], bfr[4];
#pragma unroll
    for (int i = 0; i < 4; i++)
      af[i] = *(const short8*)(&As[(wr + 16 * i + lm) * 32 + lq * 8]);
#pragma unroll
    for (int j = 0; j < 4; j++)
      bfr[j] = *(const short8*)(&Bs[(wc + 16 * j + lm) * 32 + lq * 8]);
#pragma unroll
    for (int i = 0; i < 4; i++)
#pragma unroll
      for (int j = 0; j < 4; j++) acc[i][j] = mfma16(af[i], bfr[j], acc[i][j]);
    __syncthreads();
  }

#pragma unroll
  for (int i = 0; i < 4; i++) {
#pragma unroll
    for (int j = 0; j < 4; j++) {
      const int col = col0 + wc + 16 * j + lm;
      const float bs = bias[col];
#pragma unroll
      for (int r = 0; r < 4; r++) {
        const int row = row0 + wr + 16 * i + lq * 4 + r;
        float v = acc[i][j][r] + bs;
        if (RELU) v = fmaxf(v, 0.f);
        if (OUT_BF16)
          Cb[(size_t)row * N + col] = f2bs(v);
        else
          Cf[(size_t)row * N + col] = v;
      }
    }
  }
}

// ---------------------------------------------------------------------------
// Split-K GEMM 128x128: block z covers K range [z*Kslice, (z+1)*Kslice),
// writes f32 partial (no bias) to Cf + z*M*N. No atomics.
// ---------------------------------------------------------------------------
__global__ __launch_bounds__(256) void gemm_bt_part(
    const short* __restrict__ A, const short* __restrict__ Bt,
    float* __restrict__ Cf, int M, int N, int K, int Kslice) {
  __shared__ __attribute__((aligned(16))) short As[128 * 32];
  __shared__ __attribute__((aligned(16))) short Bs[128 * 32];

  const int tid = threadIdx.x;
  const int wave = tid >> 6, lane = tid & 63;
  const int lm = lane & 15, lq = lane >> 4;
  const int row0 = blockIdx.y * 128, col0 = blockIdx.x * 128;
  const int kbase = blockIdx.z * Kslice;
  const int wr = (wave >> 1) * 64, wc = (wave & 1) * 64;
  Cf += (size_t)blockIdx.z * M * N;

  const short* ag = A + (size_t)(row0 + wave * 32 + (lane >> 2)) * K + (lane & 3) * 8;
  const short* bg = Bt + (size_t)(col0 + wave * 32 + (lane >> 2)) * K + (lane & 3) * 8;
  short* asl = &As[wave * 32 * 32];
  short* bsl = &Bs[wave * 32 * 32];

  f32x4 acc[4][4];
#pragma unroll
  for (int i = 0; i < 4; i++)
#pragma unroll
    for (int j = 0; j < 4; j++) acc[i][j] = (f32x4){0.f, 0.f, 0.f, 0.f};

  for (int k0 = kbase; k0 < kbase + Kslice; k0 += 32) {
    load_lds16(ag + k0, asl);
    load_lds16(ag + (size_t)16 * K + k0, asl + 16 * 32);
    load_lds16(bg + k0, bsl);
    load_lds16(bg + (size_t)16 * K + k0, bsl + 16 * 32);
    __syncthreads();

    short8 af[4], bfr[4];
#pragma unroll
    for (int i = 0; i < 4; i++)
      af[i] = *(const short8*)(&As[(wr + 16 * i + lm) * 32 + lq * 8]);
#pragma unroll
    for (int j = 0; j < 4; j++)
      bfr[j] = *(const short8*)(&Bs[(wc + 16 * j + lm) * 32 + lq * 8]);
#pragma unroll
    for (int i = 0; i < 4; i++)
#pragma unroll
      for (int j = 0; j < 4; j++) acc[i][j] = mfma16(af[i], bfr[j], acc[i][j]);
    __syncthreads();
  }

#pragma unroll
  for (int i = 0; i < 4; i++) {
#pragma unroll
    for (int j = 0; j < 4; j++) {
      const int col = col0 + wc + 16 * j + lm;
#pragma unroll
      for (int r = 0; r < 4; r++) {
        const int row = row0 + wr + 16 * i + lq * 4 + r;
        Cf[(size_t)row * N + col] = acc[i][j][r];
      }
    }
  }
}

// ---------------------------------------------------------------------------
// Fused attention, S^T form, non-online softmax, split-K x4, KVBLK=32.
//
// R6: ONE change vs R5 — __launch_bounds__(256, 8). Evidence across
// R0/R2/R4/R5: measured residency tracks the 2nd launch_bounds arg exactly
// (3->3 blocks/CU, 4->4) even when LDS would allow 5 or 10 blocks; i.e. on
// this toolchain the waves-per-eu emission CAPS occupancy rather than just
// flooring the register allocator. This kernel is 56 VGPR, so requesting
// 8 waves/EU (VGPR cap 64) is spill-safe — unlike R3's ~100-reg kernel
// where the same request forced a catastrophic spill. 16 KB LDS x 8 blocks
// = 128 KB <= 160 KB; grid 2048 = exactly 8 blocks/CU, one round.
// Check on failure: if occupancy still ~40%, the cap hypothesis is refuted
// -> residency limited elsewhere (HW WG dispatch), restructure instead.
// ---------------------------------------------------------------------------
__global__ __launch_bounds__(256, 8) void attn_kernel(
    const short* __restrict__ QKV,   // [NTOK][3072]: Q*0.125 | K | V
    const short* __restrict__ VT,    // [DMODEL][NTOK]
    const short* __restrict__ corrb, // [B][S][S] bf16
    float* __restrict__ Op,          // [NSPLIT][NTOK][DMODEL] partial numerators
    float* __restrict__ lp) {        // [NSPLIT][NTOK][NHEAD] partial denominators
  const int h = blockIdx.x, qtile = blockIdx.y;
  const int b = blockIdx.z >> 2, split = blockIdx.z & 3;
  const int koff = split * (S_LEN / NSPLIT);
  const int tid = threadIdx.x;
  const int wave = tid >> 6, lane = tid & 63;
  const int lm = lane & 15, lq = lane >> 4;
  const int qb = qtile * 128 + wave * 32;
  const int fx = lm & 7;         // K-tile read swizzle key (8 units/row)
  const int fy = (lm >> 1) & 3;  // V/P read swizzle key (4 units/row)

  __shared__ __attribute__((aligned(16))) short Ks[32 * 64];     // 4 KB
  __shared__ __attribute__((aligned(16))) short Vs[64 * 32];     // 4 KB
  __shared__ __attribute__((aligned(16))) short Ps[4 * 32 * 32]; // 8 KB

  const short* q0 = QKV + (size_t)(b * S_LEN + qb + lm) * QKVLD + h * DHEAD;
  const short* q1 = q0 + (size_t)16 * QKVLD;
  const short8 qA0 = *(const short8*)(q0 + lq * 8);
  const short8 qA1 = *(const short8*)(q0 + lq * 8 + 32);
  const short8 qB0 = *(const short8*)(q1 + lq * 8);
  const short8 qB1 = *(const short8*)(q1 + lq * 8 + 32);

  f32x4 oA[4], oB[4];
#pragma unroll
  for (int t = 0; t < 4; t++) {
    oA[t] = (f32x4){0.f, 0.f, 0.f, 0.f};
    oB[t] = (f32x4){0.f, 0.f, 0.f, 0.f};
  }
  f32x4 laccA = (f32x4){0.f, 0.f, 0.f, 0.f};
  f32x4 laccB = (f32x4){0.f, 0.f, 0.f, 0.f};

  const short* Kp = QKV + (size_t)(b * S_LEN) * QKVLD + DMODEL + h * DHEAD;
  const short* Vp = VT + (size_t)(h * DHEAD) * NTOK + b * S_LEN;
  const short* c0 = corrb + (size_t)(b * S_LEN + qb + lm) * S_LEN;
  const short* c1 = c0 + (size_t)16 * S_LEN;

  // --- staging geometry (256 threads, one int4 each per tile):
  // K: 32 rows x 8 units; thread (krow=tid>>3, ku=tid&7); phys = ku^(krow&7)
  // V: 64 rows x 4 units; thread (vrow=tid>>2, vu=tid&3); phys = vu^((vrow>>1)&3)
  const int krow = tid >> 3, ku = tid & 7;
  const int kws = krow * 64 + ((ku ^ (krow & 7)) * 8);
  const short* kgp = Kp + (size_t)krow * QKVLD + ku * 8;
  const int vrow = tid >> 2, vu = tid & 3;
  const int vws = vrow * 32 + ((vu ^ ((vrow >> 1) & 3)) * 8);
  const short* vgp = Vp + (size_t)vrow * NTOK + vu * 8;

  for (int kt = koff; kt < koff + S_LEN / NSPLIT; kt += 32) {
    *(int4*)(&Ks[kws]) = *(const int4*)(kgp + (size_t)kt * QKVLD);
    *(int4*)(&Vs[vws]) = *(const int4*)(vgp + kt);
    __syncthreads();

    // --- scores S^T for both q-groups (swizzled K frag reads)
    f32x4 svA[2], svB[2];
    __builtin_amdgcn_s_setprio(1);
#pragma unroll
    for (int t = 0; t < 2; t++) {
      const int rb = (t * 16 + lm) * 64;
      const short8 kf0 = *(const short8*)(&Ks[rb + (lq ^ fx) * 8]);
      const short8 kf1 = *(const short8*)(&Ks[rb + ((lq + 4) ^ fx) * 8]);
      f32x4 a = (f32x4){0.f, 0.f, 0.f, 0.f};
      a = mfma16(kf0, qA0, a);
      a = mfma16(kf1, qA1, a);
      svA[t] = a;
      f32x4 c = (f32x4){0.f, 0.f, 0.f, 0.f};
      c = mfma16(kf0, qB0, c);
      c = mfma16(kf1, qB1, c);
      svB[t] = c;
    }
    __builtin_amdgcn_s_setprio(0);

    // --- exp(s + corr), accumulate row sums, pack P (swizzled, wave-private)
#pragma unroll
    for (int t = 0; t < 2; t++) {
      const short4v crA = *(const short4v*)(c0 + kt + t * 16 + lq * 4);
      const short4v crB = *(const short4v*)(c1 + kt + t * 16 + lq * 4);
#pragma unroll
      for (int r = 0; r < 4; r++) {
        svA[t][r] = __expf(svA[t][r] + bs2f(crA[r]));
        svB[t][r] = __expf(svB[t][r] + bs2f(crB[r]));
      }
      laccA += svA[t];
      laccB += svB[t];
      short4v pA = {f2bs(svA[t][0]), f2bs(svA[t][1]), f2bs(svA[t][2]), f2bs(svA[t][3])};
      short4v pB = {f2bs(svB[t][0]), f2bs(svB[t][1]), f2bs(svB[t][2]), f2bs(svB[t][3])};
      const int pu = ((2 * t + (lq >> 1)) ^ fy) * 8 + (lq & 1) * 4;
      *(short4v*)(&Ps[wave * 1024 + lm * 32 + pu]) = pA;
      *(short4v*)(&Ps[wave * 1024 + (16 + lm) * 32 + pu]) = pB;
    }

    // --- PV (swizzled P and V frag reads; K-contraction = 32 tokens)
    const int pbA = wave * 1024 + lm * 32;
    const int pbB = pbA + 16 * 32;
    const short8 pA0 = *(const short8*)(&Ps[pbA + (lq ^ fy) * 8]);
    const short8 pB0 = *(const short8*)(&Ps[pbB + (lq ^ fy) * 8]);
    __builtin_amdgcn_s_setprio(1);
#pragma unroll
    for (int t = 0; t < 4; t++) {
      const int vrb = (t * 16 + lm) * 32;
      const short8 vf0 = *(const short8*)(&Vs[vrb + (lq ^ fy) * 8]);
      oA[t] = mfma16(vf0, pA0, oA[t]);
      oB[t] = mfma16(vf0, pB0, oB[t]);
    }
    __builtin_amdgcn_s_setprio(0);
    __syncthreads();
  }

  // --- epilogue: partial sums out (no divide)
  float lA = laccA[0] + laccA[1] + laccA[2] + laccA[3];
  float lB = laccB[0] + laccB[1] + laccB[2] + laccB[3];
  lA += __shfl_xor(lA, 16);
  lA += __shfl_xor(lA, 32);
  lB += __shfl_xor(lB, 16);
  lB += __shfl_xor(lB, 32);
  if (lq == 0) {
    lp[((size_t)split * NTOK + b * S_LEN + qb + lm) * NHEAD + h] = lA;
    lp[((size_t)split * NTOK + b * S_LEN + qb + 16 + lm) * NHEAD + h] = lB;
  }
  float* opA = Op + (size_t)split * NTOK * DMODEL +
               (size_t)(b * S_LEN + qb + lm) * DMODEL + h * DHEAD;
  float* opB = opA + (size_t)16 * DMODEL;
#pragma unroll
  for (int t = 0; t < 4; t++) {
    *(f32x4*)(opA + t * 16 + lq * 4) = oA[t];
    *(f32x4*)(opB + t * 16 + lq * 4) = oB[t];
  }
}

// ---------------------------------------------------------------------------
// Combine split-K partials: ctx = (O0+..+O3)/(l0+..+l3), bf16
// ---------------------------------------------------------------------------
__global__ __launch_bounds__(256) void combine_ctx(
    const float* __restrict__ Op, const float* __restrict__ lp,
    short* __restrict__ ctx) {
  const size_t idx = ((size_t)blockIdx.x * 256 + threadIdx.x) * 4;
  const int token = (int)(idx >> 10);
  const int d = (int)(idx & 1023);
  const int h = d >> 6;
  f32x4 o = (f32x4){0.f, 0.f, 0.f, 0.f};
  float l = 0.f;
#pragma unroll
  for (int s = 0; s < NSPLIT; s++) {
    o += *(const f32x4*)(Op + (size_t)s * NTOK * DMODEL + idx);
    l += lp[((size_t)s * NTOK + token) * NHEAD + h];
  }
  const float inv = 1.0f / l;
  short4v ov = {f2bs(o[0] * inv), f2bs(o[1] * inv),
                f2bs(o[2] * inv), f2bs(o[3] * inv)};
  *(short4v*)(ctx + idx) = ov;
}

// ---------------------------------------------------------------------------
// Residual + 2 GEMM partials + bias + LayerNorm. One block per token row.
// v = xa + p0 + p1 + bias; out = LN(v)*g + be
// ---------------------------------------------------------------------------
__global__ __launch_bounds__(256) void residual_ln3(
    const float* __restrict__ xa, const float* __restrict__ p0,
    const float* __restrict__ p1, const float* __restrict__ bias,
    const float* __restrict__ g, const float* __restrict__ be,
    float* __restrict__ outf, short* __restrict__ outb) {
  const int row = blockIdx.x;
  const int t = threadIdx.x;
  const size_t base = (size_t)row * DMODEL + t * 4;
  float4 a = *(const float4*)(xa + base);
  f32x4 q0 = *(const f32x4*)(p0 + base);
  f32x4 q1 = *(const f32x4*)(p1 + base);
  f32x4 bb = *(const f32x4*)(bias + t * 4);
  const float v0 = a.x + q0[0] + q1[0] + bb[0];
  const float v1 = a.y + q0[1] + q1[1] + bb[1];
  const float v2 = a.z + q0[2] + q1[2] + bb[2];
  const float v3 = a.w + q0[3] + q1[3] + bb[3];
  float sum = v0 + v1 + v2 + v3;
  float sq = v0 * v0 + v1 * v1 + v2 * v2 + v3 * v3;
#pragma unroll
  for (int off = 1; off < 64; off <<= 1) {
    sum += __shfl_xor(sum, off);
    sq += __shfl_xor(sq, off);
  }
  __shared__ float ssum[4], ssq[4];
  const int wave = t >> 6;
  if ((t & 63) == 0) { ssum[wave] = sum; ssq[wave] = sq; }
  __syncthreads();
  sum = ssum[0] + ssum[1] + ssum[2] + ssum[3];
  sq = ssq[0] + ssq[1] + ssq[2] + ssq[3];
  const float mean = sum * (1.0f / DMODEL);
  const float var = sq * (1.0f / DMODEL) - mean * mean;
  const float rstd = rsqrtf(var + 1e-5f);
  float4 gv = *(const float4*)(g + t * 4);
  float4 bv = *(const float4*)(be + t * 4);
  const float o0 = (v0 - mean) * rstd * gv.x + bv.x;
  const float o1 = (v1 - mean) * rstd * gv.y + bv.y;
  const float o2 = (v2 - mean) * rstd * gv.z + bv.z;
  const float o3 = (v3 - mean) * rstd * gv.w + bv.w;
  if (outf) {
    float4 ov = {o0, o1, o2, o3};
    *(float4*)(outf + base) = ov;
  }
  if (outb) {
    short4v ob = {f2bs(o0), f2bs(o1), f2bs(o2), f2bs(o3)};
    *(short4v*)(outb + base) = ob;
  }
}

// ---------------------------------------------------------------------------
extern "C" void kernel_launch(void* const* d_in, const int* in_sizes, int n_in,
                              void* d_out, int out_size, void* d_ws, size_t ws_size,
                              hipStream_t stream) {
  const float* src = (const float*)d_in[0];
  const float* corr = (const float*)d_in[1];
  const float* pos = (const float*)d_in[2];
  const float* Wq = (const float*)d_in[3];
  const float* bq = (const float*)d_in[4];
  const float* Wk = (const float*)d_in[5];
  const float* bk = (const float*)d_in[6];
  const float* Wv = (const float*)d_in[7];
  const float* bv = (const float*)d_in[8];
  const float* Wo = (const float*)d_in[9];
  const float* bo = (const float*)d_in[10];
  const float* W1 = (const float*)d_in[11];
  const float* b1 = (const float*)d_in[12];
  const float* W2 = (const float*)d_in[13];
  const float* b2 = (const float*)d_in[14];
  const float* g1 = (const float*)d_in[15];
  const float* be1 = (const float*)d_in[16];
  const float* g2 = (const float*)d_in[17];
  const float* be2 = (const float*)d_in[18];
  float* out = (float*)d_out;

  char* ws = (char*)d_ws;
  size_t off = 0;
  auto alloc = [&](size_t bytes) {
    char* p = ws + off;
    off += (bytes + 255) & ~(size_t)255;
    return p;
  };
  short* WqkvT = (short*)alloc((size_t)QKVLD * DMODEL * 2);  // [3072][1024]
  short* WoT = (short*)alloc((size_t)DMODEL * DMODEL * 2);
  short* W1T = (short*)alloc((size_t)DFF * DMODEL * 2);
  short* W2T = (short*)alloc((size_t)DMODEL * DFF * 2);
  float* bqkv = (float*)alloc((size_t)QKVLD * 4);
  short* qkb = (short*)alloc((size_t)NTOK * DMODEL * 2);
  short* srcb = (short*)alloc((size_t)NTOK * DMODEL * 2);
  short* QKVb = (short*)alloc((size_t)NTOK * QKVLD * 2);   // fused Q|K|V (24 MB)
  short* VTt = (short*)alloc((size_t)DMODEL * NTOK * 2);
  short* corrb = (short*)alloc((size_t)BATCH * S_LEN * S_LEN * 2);  // 16.8 MB
  short* ctxb = (short*)alloc((size_t)NTOK * DMODEL * 2);
  float* lp = (float*)alloc((size_t)NSPLIT * NTOK * NHEAD * 4);
  // Contiguous 67.1 MB region: [Pp: 33.55 MB][Hb: 33.55 MB].
  // attn's Op ([NSPLIT][NTOK][DMODEL] f32 = 67.1 MB) aliases the WHOLE
  // region (dead before Wo-part writes Pp and FFN1 writes Hb; FFN2 reads
  // Hb-half while writing Pp-half — disjoint).
  float* Pp = (float*)alloc((size_t)2 * NTOK * DMODEL * 4);  // 33,554,432 B
  short* Hb = (short*)alloc((size_t)NTOK * DFF * 2);         // 33,554,432 B
  float* Op = Pp;                                            // 67.1 MB alias
  float* x1f = (float*)alloc((size_t)NTOK * DMODEL * 4);
  short* x1b = (short*)alloc((size_t)NTOK * DMODEL * 2);

  const dim3 tb(32, 8);
  transpose_cast<<<dim3(32, 32), tb, 0, stream>>>(Wq, WqkvT, DMODEL, DMODEL, 0.125f);
  transpose_cast<<<dim3(32, 32), tb, 0, stream>>>(Wk, WqkvT + (size_t)DMODEL * DMODEL,
                                                  DMODEL, DMODEL, 1.0f);
  transpose_cast<<<dim3(32, 32), tb, 0, stream>>>(Wv, WqkvT + (size_t)2 * DMODEL * DMODEL,
                                                  DMODEL, DMODEL, 1.0f);
  transpose_cast<<<dim3(32, 32), tb, 0, stream>>>(Wo, WoT, DMODEL, DMODEL, 1.0f);
  transpose_cast<<<dim3(128, 32), tb, 0, stream>>>(W1, W1T, DMODEL, DFF, 1.0f);
  transpose_cast<<<dim3(32, 128), tb, 0, stream>>>(W2, W2T, DFF, DMODEL, 1.0f);
  concat_bias<<<QKVLD / 256, 256, 0, stream>>>(bq, bk, bv, bqkv);

  prep_tokens<<<(NTOK * DMODEL) / (256 * 4), 256, 0, stream>>>(src, pos, qkb, srcb);
  prep_corr<<<(BATCH * S_LEN * S_LEN) / (256 * 4), 256, 0, stream>>>(corr, corrb);

  // fused Q|K|V projection: cols<2048 use qkb, cols>=2048 use srcb
  gemm_bt<0, 1><<<dim3(QKVLD / 128, NTOK / 128), 256, 0, stream>>>(
      qkb, srcb, WqkvT, bqkv, nullptr, QKVb, NTOK, QKVLD, DMODEL, 2048);

  // V^T for attention PV a-operand (V = cols 2048.. of QKVb)
  transpose_bf16<<<dim3(DMODEL / 64, NTOK / 64), 256, 0, stream>>>(
      QKVb + 2048, VTt, NTOK, QKVLD);

  // attention, split-K x4 (2048 blocks, 16 KB LDS, target 8 blocks/CU)
  attn_kernel<<<dim3(NHEAD, S_LEN / 128, BATCH * NSPLIT), 256, 0, stream>>>(
      QKVb, VTt, corrb, Op, lp);
  combine_ctx<<<(NTOK * DMODEL) / (256 * 4), 256, 0, stream>>>(Op, lp, ctxb);

  // output projection: split-K x2 partials, summed in LN1
  gemm_bt_part<<<dim3(DMODEL / 128, NTOK / 128, 2), 256, 0, stream>>>(
      ctxb, WoT, Pp, NTOK, DMODEL, DMODEL, DMODEL / 2);

  // LN1: x1 = LN(src + P0 + P1 + bo)
  residual_ln3<<<NTOK, 256, 0, stream>>>(src, Pp, Pp + (size_t)NTOK * DMODEL,
                                         bo, g1, be1, x1f, x1b);

  // FFN1 (128x128, 1024 blocks)
  gemm_bt<1, 1><<<dim3(DFF / 128, NTOK / 128), 256, 0, stream>>>(
      x1b, x1b, W1T, b1, nullptr, Hb, NTOK, DFF, DMODEL, 1 << 30);

  // FFN2: split-K x2 partials, summed in LN2
  gemm_bt_part<<<dim3(DMODEL / 128, NTOK / 128, 2), 256, 0, stream>>>(
      Hb, W2T, Pp, NTOK, DMODEL, DFF, DFF / 2);

  // LN2 -> output
  residual_ln3<<<NTOK, 256, 0, stream>>>(x1f, Pp, Pp + (size_t)NTOK * DMODEL,
                                         b2, g2, be2, out, nullptr);
}

// Round 7
// 480.687 us; speedup vs baseline: 1.8316x; 1.8316x over previous
//
#include <hip/hip_runtime.h>
#include <hip/hip_bf16.h>

#define S_LEN  2048
#define BATCH  2
#define DMODEL 1024
#define NHEAD  16
#define DHEAD  64
#define DFF    4096
#define NTOK   (BATCH * S_LEN)
#define QKVLD  3072   // fused Q|K|V output row stride
#define NSPLIT 2      // attention split-K factor

typedef __attribute__((ext_vector_type(8))) short short8;
typedef __attribute__((ext_vector_type(4))) short short4v;
typedef __attribute__((ext_vector_type(4))) float f32x4;

__device__ __forceinline__ short f2bs(float f) {
  __hip_bfloat16 h = __float2bfloat16(f);
  short s;
  __builtin_memcpy(&s, &h, sizeof(short));
  return s;
}

__device__ __forceinline__ float bs2f(short s) {
  unsigned u = ((unsigned)(unsigned short)s) << 16;
  float f;
  __builtin_memcpy(&f, &u, sizeof(float));
  return f;
}

__device__ __forceinline__ f32x4 mfma16(short8 a, short8 b, f32x4 c) {
  return __builtin_amdgcn_mfma_f32_16x16x32_bf16(a, b, c, 0, 0, 0);
}

// async global->LDS, 16B per lane; LDS dest = wave-uniform base + lane*16
__device__ __forceinline__ void load_lds16(const short* g, short* l) {
  __builtin_amdgcn_global_load_lds(
      (const __attribute__((address_space(1))) void*)g,
      (__attribute__((address_space(3))) void*)l, 16, 0, 0);
}

// ---------------------------------------------------------------------------
// Weight transpose + cast + scale: in f32 [R][C] -> out bf16 [C][R] * scale
// ---------------------------------------------------------------------------
__global__ void transpose_cast(const float* __restrict__ in, short* __restrict__ out,
                               int R, int C, float scale) {
  __shared__ float tile[32][33];
  const int c0 = blockIdx.x * 32, r0 = blockIdx.y * 32;
  const int tx = threadIdx.x, ty = threadIdx.y;  // 32 x 8
#pragma unroll
  for (int i = 0; i < 32; i += 8)
    tile[ty + i][tx] = in[(size_t)(r0 + ty + i) * C + c0 + tx];
  __syncthreads();
#pragma unroll
  for (int i = 0; i < 32; i += 8)
    out[(size_t)(c0 + ty + i) * R + r0 + tx] = f2bs(tile[tx][ty + i] * scale);
}

// ---------------------------------------------------------------------------
// bf16 transpose: in [R][LDin] -> out [C][R], 64x64 tiles
// ---------------------------------------------------------------------------
__global__ __launch_bounds__(256) void transpose_bf16(
    const short* __restrict__ in, short* __restrict__ out, int R, int LDin) {
  __shared__ __attribute__((aligned(16))) short tile[64][72];
  const int c0 = blockIdx.x * 64, r0 = blockIdx.y * 64;
#pragma unroll
  for (int i = 0; i < 2; i++) {
    const int idx = threadIdx.x + 256 * i;
    const int rr = idx >> 3, cc8 = (idx & 7) * 8;
    *(int4*)(&tile[rr][cc8]) = *(const int4*)(in + (size_t)(r0 + rr) * LDin + c0 + cc8);
  }
  __syncthreads();
#pragma unroll
  for (int i = 0; i < 2; i++) {
    const int idx = threadIdx.x + 256 * i;
    const int rr = idx >> 3, cc8 = (idx & 7) * 8;
    short8 v;
#pragma unroll
    for (int j = 0; j < 8; j++) v[j] = tile[cc8 + j][rr];
    *(short8*)(out + (size_t)(c0 + rr) * R + r0 + cc8) = v;
  }
}

// ---------------------------------------------------------------------------
// bqkv: [0,1024)=bq*0.125, [1024,2048)=bk, [2048,3072)=bv
// ---------------------------------------------------------------------------
__global__ void concat_bias(const float* __restrict__ bq, const float* __restrict__ bk,
                            const float* __restrict__ bv, float* __restrict__ bqkv) {
  const int i = blockIdx.x * 256 + threadIdx.x;
  float v;
  if (i < DMODEL) v = bq[i] * 0.125f;
  else if (i < 2 * DMODEL) v = bk[i - DMODEL];
  else v = bv[i - 2 * DMODEL];
  bqkv[i] = v;
}

// ---------------------------------------------------------------------------
// Token prep: qkb = bf16(src+pos), srcb = bf16(src)
// ---------------------------------------------------------------------------
__global__ void prep_tokens(const float* __restrict__ src, const float* __restrict__ pos,
                            short* __restrict__ qkb, short* __restrict__ srcb) {
  const int i = (blockIdx.x * blockDim.x + threadIdx.x) * 4;
  float4 s = *(const float4*)(src + i);
  float4 p = *(const float4*)(pos + i);
  short4v q4 = {f2bs(s.x + p.x), f2bs(s.y + p.y), f2bs(s.z + p.z), f2bs(s.w + p.w)};
  short4v s4 = {f2bs(s.x), f2bs(s.y), f2bs(s.z), f2bs(s.w)};
  *(short4v*)(qkb + i) = q4;
  *(short4v*)(srcb + i) = s4;
}

// ---------------------------------------------------------------------------
// corr f32 -> bf16
// ---------------------------------------------------------------------------
__global__ void prep_corr(const float* __restrict__ corr, short* __restrict__ corrb) {
  const size_t i = ((size_t)blockIdx.x * 256 + threadIdx.x) * 4;
  float4 c = *(const float4*)(corr + i);
  short4v o = {f2bs(c.x), f2bs(c.y), f2bs(c.z), f2bs(c.w)};
  *(short4v*)(corrb + i) = o;
}

// ---------------------------------------------------------------------------
// GEMM 128x128 (m97-style), dual-A: column blocks with col0 < splitcol read
// A0, others A1 (for fused QKV: Q/K from src+pos, V from src).
// ---------------------------------------------------------------------------
template <int RELU, int OUT_BF16>
__global__ __launch_bounds__(256) void gemm_bt(
    const short* __restrict__ A0, const short* __restrict__ A1,
    const short* __restrict__ Bt, const float* __restrict__ bias,
    float* __restrict__ Cf, short* __restrict__ Cb,
    int M, int N, int K, int splitcol) {
  __shared__ __attribute__((aligned(16))) short As[128 * 32];
  __shared__ __attribute__((aligned(16))) short Bs[128 * 32];

  const int tid = threadIdx.x;
  const int wave = tid >> 6, lane = tid & 63;
  const int lm = lane & 15, lq = lane >> 4;
  const int row0 = blockIdx.y * 128, col0 = blockIdx.x * 128;
  const int wr = (wave >> 1) * 64, wc = (wave & 1) * 64;

  const short* A = (col0 < splitcol) ? A0 : A1;
  const short* ag = A + (size_t)(row0 + wave * 32 + (lane >> 2)) * K + (lane & 3) * 8;
  const short* bg = Bt + (size_t)(col0 + wave * 32 + (lane >> 2)) * K + (lane & 3) * 8;
  short* asl = &As[wave * 32 * 32];
  short* bsl = &Bs[wave * 32 * 32];

  f32x4 acc[4][4];
#pragma unroll
  for (int i = 0; i < 4; i++)
#pragma unroll
    for (int j = 0; j < 4; j++) acc[i][j] = (f32x4){0.f, 0.f, 0.f, 0.f};

  for (int k0 = 0; k0 < K; k0 += 32) {
    load_lds16(ag + k0, asl);
    load_lds16(ag + (size_t)16 * K + k0, asl + 16 * 32);
    load_lds16(bg + k0, bsl);
    load_lds16(bg + (size_t)16 * K + k0, bsl + 16 * 32);
    __syncthreads();

    short8 af[4], bfr[4];
#pragma unroll
    for (int i = 0; i < 4; i++)
      af[i] = *(const short8*)(&As[(wr + 16 * i + lm) * 32 + lq * 8]);
#pragma unroll
    for (int j = 0; j < 4; j++)
      bfr[j] = *(const short8*)(&Bs[(wc + 16 * j + lm) * 32 + lq * 8]);
#pragma unroll
    for (int i = 0; i < 4; i++)
#pragma unroll
      for (int j = 0; j < 4; j++) acc[i][j] = mfma16(af[i], bfr[j], acc[i][j]);
    __syncthreads();
  }

#pragma unroll
  for (int i = 0; i < 4; i++) {
#pragma unroll
    for (int j = 0; j < 4; j++) {
      const int col = col0 + wc + 16 * j + lm;
      const float bs = bias[col];
#pragma unroll
      for (int r = 0; r < 4; r++) {
        const int row = row0 + wr + 16 * i + lq * 4 + r;
        float v = acc[i][j][r] + bs;
        if (RELU) v = fmaxf(v, 0.f);
        if (OUT_BF16)
          Cb[(size_t)row * N + col] = f2bs(v);
        else
          Cf[(size_t)row * N + col] = v;
      }
    }
  }
}

// ---------------------------------------------------------------------------
// Split-K GEMM 128x128: block z covers K range [z*Kslice, (z+1)*Kslice),
// writes f32 partial (no bias) to Cf + z*M*N. No atomics.
// ---------------------------------------------------------------------------
__global__ __launch_bounds__(256) void gemm_bt_part(
    const short* __restrict__ A, const short* __restrict__ Bt,
    float* __restrict__ Cf, int M, int N, int K, int Kslice) {
  __shared__ __attribute__((aligned(16))) short As[128 * 32];
  __shared__ __attribute__((aligned(16))) short Bs[128 * 32];

  const int tid = threadIdx.x;
  const int wave = tid >> 6, lane = tid & 63;
  const int lm = lane & 15, lq = lane >> 4;
  const int row0 = blockIdx.y * 128, col0 = blockIdx.x * 128;
  const int kbase = blockIdx.z * Kslice;
  const int wr = (wave >> 1) * 64, wc = (wave & 1) * 64;
  Cf += (size_t)blockIdx.z * M * N;

  const short* ag = A + (size_t)(row0 + wave * 32 + (lane >> 2)) * K + (lane & 3) * 8;
  const short* bg = Bt + (size_t)(col0 + wave * 32 + (lane >> 2)) * K + (lane & 3) * 8;
  short* asl = &As[wave * 32 * 32];
  short* bsl = &Bs[wave * 32 * 32];

  f32x4 acc[4][4];
#pragma unroll
  for (int i = 0; i < 4; i++)
#pragma unroll
    for (int j = 0; j < 4; j++) acc[i][j] = (f32x4){0.f, 0.f, 0.f, 0.f};

  for (int k0 = kbase; k0 < kbase + Kslice; k0 += 32) {
    load_lds16(ag + k0, asl);
    load_lds16(ag + (size_t)16 * K + k0, asl + 16 * 32);
    load_lds16(bg + k0, bsl);
    load_lds16(bg + (size_t)16 * K + k0, bsl + 16 * 32);
    __syncthreads();

    short8 af[4], bfr[4];
#pragma unroll
    for (int i = 0; i < 4; i++)
      af[i] = *(const short8*)(&As[(wr + 16 * i + lm) * 32 + lq * 8]);
#pragma unroll
    for (int j = 0; j < 4; j++)
      bfr[j] = *(const short8*)(&Bs[(wc + 16 * j + lm) * 32 + lq * 8]);
#pragma unroll
    for (int i = 0; i < 4; i++)
#pragma unroll
      for (int j = 0; j < 4; j++) acc[i][j] = mfma16(af[i], bfr[j], acc[i][j]);
    __syncthreads();
  }

#pragma unroll
  for (int i = 0; i < 4; i++) {
#pragma unroll
    for (int j = 0; j < 4; j++) {
      const int col = col0 + wc + 16 * j + lm;
#pragma unroll
      for (int r = 0; r < 4; r++) {
        const int row = row0 + wr + 16 * i + lq * 4 + r;
        Cf[(size_t)row * N + col] = acc[i][j][r];
      }
    }
  }
}

// ---------------------------------------------------------------------------
// Fused attention, S^T form, non-online softmax, split-K x2, KVBLK=32.
//
// R7: fit the 8-waves/SIMD register budget. R6 proved launch_bounds' 2nd
// arg sets residency exactly (occupancy 41->77%) AND that 8 waves/EU means
// TOTAL (arch+accum) <= 64 VGPR/wave — R5's structure needs ~88 (56 arch +
// 32 acc) -> spilled to 32 arch (WRITE 1 GB). Fix: 512-thread blocks, 8
// waves, each wave owns 16 q-rows (half of R5's 32): acc 16 AGPR, Q 8
// VGPR, sv 8, state ~40 arch + 20 acc ~= 60 <= 64. LDS: Ks 4K + Vs 4K +
// Ps[8][16][32] 8K = 16 KB; 4 blocks/CU x 8 waves = 32 waves/CU. Staging:
// waves 0-3 K, waves 4-7 V (wave-uniform; one pointer+stride per thread).
// NSPLIT back to 2: grid (16,16,4)=1024 blocks of 512 = exactly 4/CU, and
// Op partial traffic halves. Spill check on failure: WRITE_SIZE >> 40 MB.
// ---------------------------------------------------------------------------
__global__ __launch_bounds__(512, 8) void attn_kernel(
    const short* __restrict__ QKV,   // [NTOK][3072]: Q*0.125 | K | V
    const short* __restrict__ VT,    // [DMODEL][NTOK]
    const short* __restrict__ corrb, // [B][S][S] bf16
    float* __restrict__ Op,          // [NSPLIT][NTOK][DMODEL] partial numerators
    float* __restrict__ lp) {        // [NSPLIT][NTOK][NHEAD] partial denominators
  const int h = blockIdx.x, qtile = blockIdx.y;
  const int b = blockIdx.z >> 1, split = blockIdx.z & 1;
  const int koff = split * (S_LEN / NSPLIT);
  const int tid = threadIdx.x;
  const int wave = tid >> 6, lane = tid & 63;
  const int lm = lane & 15, lq = lane >> 4;
  const int qb = qtile * 128 + wave * 16;
  const int fx = lm & 7;         // K-tile read swizzle key (8 units/row)
  const int fy = (lm >> 1) & 3;  // V/P read swizzle key (4 units/row)

  __shared__ __attribute__((aligned(16))) short Ks[32 * 64];      // 4 KB
  __shared__ __attribute__((aligned(16))) short Vs[64 * 32];      // 4 KB
  __shared__ __attribute__((aligned(16))) short Ps[8 * 16 * 32];  // 8 KB

  const short* q0 = QKV + (size_t)(b * S_LEN + qb + lm) * QKVLD + h * DHEAD;
  const short8 qA0 = *(const short8*)(q0 + lq * 8);
  const short8 qA1 = *(const short8*)(q0 + lq * 8 + 32);

  f32x4 oA[4];
#pragma unroll
  for (int t = 0; t < 4; t++) oA[t] = (f32x4){0.f, 0.f, 0.f, 0.f};
  f32x4 lacc = (f32x4){0.f, 0.f, 0.f, 0.f};

  const short* c0 = corrb + (size_t)(b * S_LEN + qb + lm) * S_LEN;

  // --- staging: waves 0-3 stage K (32 rows x 8 units), waves 4-7 stage V
  // (64 rows x 4 units); 256 threads each, one int4 per tile. Wave-uniform
  // branch. Swizzle on the LDS write side; read side uses fx/fy keys.
  const int st = tid & 255;
  const bool isK = tid < 256;
  short* sdst;
  const short* sgp;
  size_t sstep;
  if (isK) {
    const int krow = st >> 3, ku = st & 7;
    sdst = &Ks[krow * 64 + ((ku ^ (krow & 7)) * 8)];
    sgp = QKV + (size_t)(b * S_LEN + koff + krow) * QKVLD + DMODEL + h * DHEAD + ku * 8;
    sstep = (size_t)32 * QKVLD;
  } else {
    const int vrow = st >> 2, vu = st & 3;
    sdst = &Vs[vrow * 32 + ((vu ^ ((vrow >> 1) & 3)) * 8)];
    sgp = VT + (size_t)(h * DHEAD + vrow) * NTOK + b * S_LEN + koff + vu * 8;
    sstep = 32;
  }

  for (int kt = koff; kt < koff + S_LEN / NSPLIT; kt += 32) {
    *(int4*)sdst = *(const int4*)sgp;
    sgp += sstep;
    __syncthreads();

    // --- scores S^T (swizzled K frag reads): 32 keys x 16 queries
    f32x4 sv[2];
    __builtin_amdgcn_s_setprio(1);
#pragma unroll
    for (int t = 0; t < 2; t++) {
      const int rb = (t * 16 + lm) * 64;
      const short8 kf0 = *(const short8*)(&Ks[rb + (lq ^ fx) * 8]);
      const short8 kf1 = *(const short8*)(&Ks[rb + ((lq + 4) ^ fx) * 8]);
      f32x4 a = (f32x4){0.f, 0.f, 0.f, 0.f};
      a = mfma16(kf0, qA0, a);
      a = mfma16(kf1, qA1, a);
      sv[t] = a;
    }
    __builtin_amdgcn_s_setprio(0);

    // --- exp(s + corr), accumulate row sums, pack P (swizzled, wave-private)
#pragma unroll
    for (int t = 0; t < 2; t++) {
      const short4v cr = *(const short4v*)(c0 + kt + t * 16 + lq * 4);
#pragma unroll
      for (int r = 0; r < 4; r++)
        sv[t][r] = __expf(sv[t][r] + bs2f(cr[r]));
      lacc += sv[t];
      short4v pA = {f2bs(sv[t][0]), f2bs(sv[t][1]), f2bs(sv[t][2]), f2bs(sv[t][3])};
      const int pu = ((2 * t + (lq >> 1)) ^ fy) * 8 + (lq & 1) * 4;
      *(short4v*)(&Ps[wave * 512 + lm * 32 + pu]) = pA;
    }

    // --- PV (swizzled P and V frag reads; K-contraction = 32 tokens)
    const short8 pA0 = *(const short8*)(&Ps[wave * 512 + lm * 32 + (lq ^ fy) * 8]);
    __builtin_amdgcn_s_setprio(1);
#pragma unroll
    for (int t = 0; t < 4; t++) {
      const int vrb = (t * 16 + lm) * 32;
      const short8 vf0 = *(const short8*)(&Vs[vrb + (lq ^ fy) * 8]);
      oA[t] = mfma16(vf0, pA0, oA[t]);
    }
    __builtin_amdgcn_s_setprio(0);
    __syncthreads();
  }

  // --- epilogue: partial sums out (no divide)
  float lA = lacc[0] + lacc[1] + lacc[2] + lacc[3];
  lA += __shfl_xor(lA, 16);
  lA += __shfl_xor(lA, 32);
  if (lq == 0)
    lp[((size_t)split * NTOK + b * S_LEN + qb + lm) * NHEAD + h] = lA;
  float* opA = Op + (size_t)split * NTOK * DMODEL +
               (size_t)(b * S_LEN + qb + lm) * DMODEL + h * DHEAD;
#pragma unroll
  for (int t = 0; t < 4; t++)
    *(f32x4*)(opA + t * 16 + lq * 4) = oA[t];
}

// ---------------------------------------------------------------------------
// Combine split-K partials: ctx = (O0+O1)/(l0+l1), bf16
// ---------------------------------------------------------------------------
__global__ __launch_bounds__(256) void combine_ctx(
    const float* __restrict__ Op, const float* __restrict__ lp,
    short* __restrict__ ctx) {
  const size_t idx = ((size_t)blockIdx.x * 256 + threadIdx.x) * 4;
  const int token = (int)(idx >> 10);
  const int d = (int)(idx & 1023);
  const int h = d >> 6;
  f32x4 o = (f32x4){0.f, 0.f, 0.f, 0.f};
  float l = 0.f;
#pragma unroll
  for (int s = 0; s < NSPLIT; s++) {
    o += *(const f32x4*)(Op + (size_t)s * NTOK * DMODEL + idx);
    l += lp[((size_t)s * NTOK + token) * NHEAD + h];
  }
  const float inv = 1.0f / l;
  short4v ov = {f2bs(o[0] * inv), f2bs(o[1] * inv),
                f2bs(o[2] * inv), f2bs(o[3] * inv)};
  *(short4v*)(ctx + idx) = ov;
}

// ---------------------------------------------------------------------------
// Residual + 2 GEMM partials + bias + LayerNorm. One block per token row.
// v = xa + p0 + p1 + bias; out = LN(v)*g + be
// ---------------------------------------------------------------------------
__global__ __launch_bounds__(256) void residual_ln3(
    const float* __restrict__ xa, const float* __restrict__ p0,
    const float* __restrict__ p1, const float* __restrict__ bias,
    const float* __restrict__ g, const float* __restrict__ be,
    float* __restrict__ outf, short* __restrict__ outb) {
  const int row = blockIdx.x;
  const int t = threadIdx.x;
  const size_t base = (size_t)row * DMODEL + t * 4;
  float4 a = *(const float4*)(xa + base);
  f32x4 q0 = *(const f32x4*)(p0 + base);
  f32x4 q1 = *(const f32x4*)(p1 + base);
  f32x4 bb = *(const f32x4*)(bias + t * 4);
  const float v0 = a.x + q0[0] + q1[0] + bb[0];
  const float v1 = a.y + q0[1] + q1[1] + bb[1];
  const float v2 = a.z + q0[2] + q1[2] + bb[2];
  const float v3 = a.w + q0[3] + q1[3] + bb[3];
  float sum = v0 + v1 + v2 + v3;
  float sq = v0 * v0 + v1 * v1 + v2 * v2 + v3 * v3;
#pragma unroll
  for (int off = 1; off < 64; off <<= 1) {
    sum += __shfl_xor(sum, off);
    sq += __shfl_xor(sq, off);
  }
  __shared__ float ssum[4], ssq[4];
  const int wave = t >> 6;
  if ((t & 63) == 0) { ssum[wave] = sum; ssq[wave] = sq; }
  __syncthreads();
  sum = ssum[0] + ssum[1] + ssum[2] + ssum[3];
  sq = ssq[0] + ssq[1] + ssq[2] + ssq[3];
  const float mean = sum * (1.0f / DMODEL);
  const float var = sq * (1.0f / DMODEL) - mean * mean;
  const float rstd = rsqrtf(var + 1e-5f);
  float4 gv = *(const float4*)(g + t * 4);
  float4 bv = *(const float4*)(be + t * 4);
  const float o0 = (v0 - mean) * rstd * gv.x + bv.x;
  const float o1 = (v1 - mean) * rstd * gv.y + bv.y;
  const float o2 = (v2 - mean) * rstd * gv.z + bv.z;
  const float o3 = (v3 - mean) * rstd * gv.w + bv.w;
  if (outf) {
    float4 ov = {o0, o1, o2, o3};
    *(float4*)(outf + base) = ov;
  }
  if (outb) {
    short4v ob = {f2bs(o0), f2bs(o1), f2bs(o2), f2bs(o3)};
    *(short4v*)(outb + base) = ob;
  }
}

// ---------------------------------------------------------------------------
extern "C" void kernel_launch(void* const* d_in, const int* in_sizes, int n_in,
                              void* d_out, int out_size, void* d_ws, size_t ws_size,
                              hipStream_t stream) {
  const float* src = (const float*)d_in[0];
  const float* corr = (const float*)d_in[1];
  const float* pos = (const float*)d_in[2];
  const float* Wq = (const float*)d_in[3];
  const float* bq = (const float*)d_in[4];
  const float* Wk = (const float*)d_in[5];
  const float* bk = (const float*)d_in[6];
  const float* Wv = (const float*)d_in[7];
  const float* bv = (const float*)d_in[8];
  const float* Wo = (const float*)d_in[9];
  const float* bo = (const float*)d_in[10];
  const float* W1 = (const float*)d_in[11];
  const float* b1 = (const float*)d_in[12];
  const float* W2 = (const float*)d_in[13];
  const float* b2 = (const float*)d_in[14];
  const float* g1 = (const float*)d_in[15];
  const float* be1 = (const float*)d_in[16];
  const float* g2 = (const float*)d_in[17];
  const float* be2 = (const float*)d_in[18];
  float* out = (float*)d_out;

  char* ws = (char*)d_ws;
  size_t off = 0;
  auto alloc = [&](size_t bytes) {
    char* p = ws + off;
    off += (bytes + 255) & ~(size_t)255;
    return p;
  };
  short* WqkvT = (short*)alloc((size_t)QKVLD * DMODEL * 2);  // [3072][1024]
  short* WoT = (short*)alloc((size_t)DMODEL * DMODEL * 2);
  short* W1T = (short*)alloc((size_t)DFF * DMODEL * 2);
  short* W2T = (short*)alloc((size_t)DMODEL * DFF * 2);
  float* bqkv = (float*)alloc((size_t)QKVLD * 4);
  short* qkb = (short*)alloc((size_t)NTOK * DMODEL * 2);
  short* srcb = (short*)alloc((size_t)NTOK * DMODEL * 2);
  short* QKVb = (short*)alloc((size_t)NTOK * QKVLD * 2);   // fused Q|K|V (24 MB)
  short* VTt = (short*)alloc((size_t)DMODEL * NTOK * 2);
  short* corrb = (short*)alloc((size_t)BATCH * S_LEN * S_LEN * 2);  // 16.8 MB
  short* ctxb = (short*)alloc((size_t)NTOK * DMODEL * 2);
  float* lp = (float*)alloc((size_t)NSPLIT * NTOK * NHEAD * 4);
  // Pp (33.55 MB) is aliased by attn's Op ([NSPLIT=2][NTOK][DMODEL] f32 =
  // 33.55 MB exactly); Op is dead before Wo-part writes Pp. Hb separate.
  float* Pp = (float*)alloc((size_t)2 * NTOK * DMODEL * 4);  // 33,554,432 B
  short* Hb = (short*)alloc((size_t)NTOK * DFF * 2);         // 33,554,432 B
  float* Op = Pp;                                            // alias
  float* x1f = (float*)alloc((size_t)NTOK * DMODEL * 4);
  short* x1b = (short*)alloc((size_t)NTOK * DMODEL * 2);

  const dim3 tb(32, 8);
  transpose_cast<<<dim3(32, 32), tb, 0, stream>>>(Wq, WqkvT, DMODEL, DMODEL, 0.125f);
  transpose_cast<<<dim3(32, 32), tb, 0, stream>>>(Wk, WqkvT + (size_t)DMODEL * DMODEL,
                                                  DMODEL, DMODEL, 1.0f);
  transpose_cast<<<dim3(32, 32), tb, 0, stream>>>(Wv, WqkvT + (size_t)2 * DMODEL * DMODEL,
                                                  DMODEL, DMODEL, 1.0f);
  transpose_cast<<<dim3(32, 32), tb, 0, stream>>>(Wo, WoT, DMODEL, DMODEL, 1.0f);
  transpose_cast<<<dim3(128, 32), tb, 0, stream>>>(W1, W1T, DMODEL, DFF, 1.0f);
  transpose_cast<<<dim3(32, 128), tb, 0, stream>>>(W2, W2T, DFF, DMODEL, 1.0f);
  concat_bias<<<QKVLD / 256, 256, 0, stream>>>(bq, bk, bv, bqkv);

  prep_tokens<<<(NTOK * DMODEL) / (256 * 4), 256, 0, stream>>>(src, pos, qkb, srcb);
  prep_corr<<<(BATCH * S_LEN * S_LEN) / (256 * 4), 256, 0, stream>>>(corr, corrb);

  // fused Q|K|V projection: cols<2048 use qkb, cols>=2048 use srcb
  gemm_bt<0, 1><<<dim3(QKVLD / 128, NTOK / 128), 256, 0, stream>>>(
      qkb, srcb, WqkvT, bqkv, nullptr, QKVb, NTOK, QKVLD, DMODEL, 2048);

  // V^T for attention PV a-operand (V = cols 2048.. of QKVb)
  transpose_bf16<<<dim3(DMODEL / 64, NTOK / 64), 256, 0, stream>>>(
      QKVb + 2048, VTt, NTOK, QKVLD);

  // attention, split-K x2 (1024 blocks x 512 thr, 16 KB LDS, 32 waves/CU)
  attn_kernel<<<dim3(NHEAD, S_LEN / 128, BATCH * NSPLIT), 512, 0, stream>>>(
      QKVb, VTt, corrb, Op, lp);
  combine_ctx<<<(NTOK * DMODEL) / (256 * 4), 256, 0, stream>>>(Op, lp, ctxb);

  // output projection: split-K x2 partials, summed in LN1
  gemm_bt_part<<<dim3(DMODEL / 128, NTOK / 128, 2), 256, 0, stream>>>(
      ctxb, WoT, Pp, NTOK, DMODEL, DMODEL, DMODEL / 2);

  // LN1: x1 = LN(src + P0 + P1 + bo)
  residual_ln3<<<NTOK, 256, 0, stream>>>(src, Pp, Pp + (size_t)NTOK * DMODEL,
                                         bo, g1, be1, x1f, x1b);

  // FFN1 (128x128, 1024 blocks)
  gemm_bt<1, 1><<<dim3(DFF / 128, NTOK / 128), 256, 0, stream>>>(
      x1b, x1b, W1T, b1, nullptr, Hb, NTOK, DFF, DMODEL, 1 << 30);

  // FFN2: split-K x2 partials, summed in LN2
  gemm_bt_part<<<dim3(DMODEL / 128, NTOK / 128, 2), 256, 0, stream>>>(
      Hb, W2T, Pp, NTOK, DMODEL, DFF, DFF / 2);

  // LN2 -> output
  residual_ln3<<<NTOK, 256, 0, stream>>>(x1f, Pp, Pp + (size_t)NTOK * DMODEL,
                                         b2, g2, be2, out, nullptr);
}

// Round 8
// 480.650 us; speedup vs baseline: 1.8318x; 1.0001x over previous
//
#include <hip/hip_runtime.h>
#include <hip/hip_bf16.h>

#define S_LEN  2048
#define BATCH  2
#define DMODEL 1024
#define NHEAD  16
#define DHEAD  64
#define DFF    4096
#define NTOK   (BATCH * S_LEN)
#define QKVLD  3072   // fused Q|K|V output row stride

typedef __attribute__((ext_vector_type(8))) short short8;
typedef __attribute__((ext_vector_type(4))) short short4v;
typedef __attribute__((ext_vector_type(4))) float f32x4;

__device__ __forceinline__ short f2bs(float f) {
  __hip_bfloat16 h = __float2bfloat16(f);
  short s;
  __builtin_memcpy(&s, &h, sizeof(short));
  return s;
}

__device__ __forceinline__ float bs2f(short s) {
  unsigned u = ((unsigned)(unsigned short)s) << 16;
  float f;
  __builtin_memcpy(&f, &u, sizeof(float));
  return f;
}

__device__ __forceinline__ f32x4 mfma16(short8 a, short8 b, f32x4 c) {
  return __builtin_amdgcn_mfma_f32_16x16x32_bf16(a, b, c, 0, 0, 0);
}

// async global->LDS, 16B per lane; LDS dest = wave-uniform base + lane*16
__device__ __forceinline__ void load_lds16(const short* g, short* l) {
  __builtin_amdgcn_global_load_lds(
      (const __attribute__((address_space(1))) void*)g,
      (__attribute__((address_space(3))) void*)l, 16, 0, 0);
}

// ---------------------------------------------------------------------------
// prep_static: ALL weight transposes + bias concat in ONE dispatch (R8:
// was 7 kernels; launch-gap savings). 1-D grid of 32x32 tiles, segment
// decoded from blockIdx.x:
//   [    0, 1024): Wq -> WqkvT[0..]        (scale 0.125)
//   [ 1024, 2048): Wk -> WqkvT[1M..]
//   [ 2048, 3072): Wv -> WqkvT[2M..]
//   [ 3072, 4096): Wo -> WoT
//   [ 4096, 8192): W1 (1024x4096) -> W1T
//   [ 8192,12288): W2 (4096x1024) -> W2T
//   [12288,12300): bqkv concat (bq*0.125 | bk | bv)
// ---------------------------------------------------------------------------
__global__ void prep_static(
    const float* __restrict__ Wq, const float* __restrict__ Wk,
    const float* __restrict__ Wv, const float* __restrict__ Wo,
    const float* __restrict__ W1, const float* __restrict__ W2,
    const float* __restrict__ bq, const float* __restrict__ bk,
    const float* __restrict__ bv,
    short* __restrict__ WqkvT, short* __restrict__ WoT,
    short* __restrict__ W1T, short* __restrict__ W2T,
    float* __restrict__ bqkv) {
  const int gid = blockIdx.x;
  const int tx = threadIdx.x, ty = threadIdx.y;  // 32 x 8

  if (gid >= 12288) {  // bias concat
    const int i = (gid - 12288) * 256 + ty * 32 + tx;
    float v;
    if (i < DMODEL) v = bq[i] * 0.125f;
    else if (i < 2 * DMODEL) v = bk[i - DMODEL];
    else v = bv[i - 2 * DMODEL];
    bqkv[i] = v;
    return;
  }

  const float* in;
  short* out;
  int R, C, t;
  float scale = 1.0f;
  if (gid < 4096) {
    t = gid & 1023;
    R = C = 1024;
    if (gid < 1024)      { in = Wq; out = WqkvT;                 scale = 0.125f; }
    else if (gid < 2048) { in = Wk; out = WqkvT + 1024 * 1024; }
    else if (gid < 3072) { in = Wv; out = WqkvT + 2 * 1024 * 1024; }
    else                 { in = Wo; out = WoT; }
  } else if (gid < 8192) {
    t = gid - 4096; in = W1; out = W1T; R = 1024; C = 4096;
  } else {
    t = gid - 8192; in = W2; out = W2T; R = 4096; C = 1024;
  }
  const int tpr = C >> 5;  // tiles per row of C
  const int c0 = (t % tpr) * 32, r0 = (t / tpr) * 32;

  __shared__ float tile[32][33];
#pragma unroll
  for (int i = 0; i < 32; i += 8)
    tile[ty + i][tx] = in[(size_t)(r0 + ty + i) * C + c0 + tx];
  __syncthreads();
#pragma unroll
  for (int i = 0; i < 32; i += 8)
    out[(size_t)(c0 + ty + i) * R + r0 + tx] = f2bs(tile[tx][ty + i] * scale);
}

// ---------------------------------------------------------------------------
// prep_inputs: tokens (qkb/srcb) + corr->bf16 in ONE dispatch.
//   gid <  4096: token path (NTOK*DMODEL elements)
//   gid >= 4096: corr path  (B*S*S elements)
// ---------------------------------------------------------------------------
__global__ void prep_inputs(const float* __restrict__ src, const float* __restrict__ pos,
                            const float* __restrict__ corr,
                            short* __restrict__ qkb, short* __restrict__ srcb,
                            short* __restrict__ corrb) {
  const int gid = blockIdx.x;
  if (gid < 4096) {
    const int i = gid * 1024 + threadIdx.x * 4;
    float4 s = *(const float4*)(src + i);
    float4 p = *(const float4*)(pos + i);
    short4v q4 = {f2bs(s.x + p.x), f2bs(s.y + p.y), f2bs(s.z + p.z), f2bs(s.w + p.w)};
    short4v s4 = {f2bs(s.x), f2bs(s.y), f2bs(s.z), f2bs(s.w)};
    *(short4v*)(qkb + i) = q4;
    *(short4v*)(srcb + i) = s4;
  } else {
    const size_t i = ((size_t)(gid - 4096)) * 1024 + threadIdx.x * 4;
    float4 c = *(const float4*)(corr + i);
    short4v o = {f2bs(c.x), f2bs(c.y), f2bs(c.z), f2bs(c.w)};
    *(short4v*)(corrb + i) = o;
  }
}

// ---------------------------------------------------------------------------
// bf16 transpose: in [R][LDin] -> out [C][R], 64x64 tiles
// ---------------------------------------------------------------------------
__global__ __launch_bounds__(256) void transpose_bf16(
    const short* __restrict__ in, short* __restrict__ out, int R, int LDin) {
  __shared__ __attribute__((aligned(16))) short tile[64][72];
  const int c0 = blockIdx.x * 64, r0 = blockIdx.y * 64;
#pragma unroll
  for (int i = 0; i < 2; i++) {
    const int idx = threadIdx.x + 256 * i;
    const int rr = idx >> 3, cc8 = (idx & 7) * 8;
    *(int4*)(&tile[rr][cc8]) = *(const int4*)(in + (size_t)(r0 + rr) * LDin + c0 + cc8);
  }
  __syncthreads();
#pragma unroll
  for (int i = 0; i < 2; i++) {
    const int idx = threadIdx.x + 256 * i;
    const int rr = idx >> 3, cc8 = (idx & 7) * 8;
    short8 v;
#pragma unroll
    for (int j = 0; j < 8; j++) v[j] = tile[cc8 + j][rr];
    *(short8*)(out + (size_t)(c0 + rr) * R + r0 + cc8) = v;
  }
}

// ---------------------------------------------------------------------------
// GEMM 128x128 (m97-style), dual-A: column blocks with col0 < splitcol read
// A0, others A1 (for fused QKV: Q/K from src+pos, V from src).
// ---------------------------------------------------------------------------
template <int RELU, int OUT_BF16>
__global__ __launch_bounds__(256) void gemm_bt(
    const short* __restrict__ A0, const short* __restrict__ A1,
    const short* __restrict__ Bt, const float* __restrict__ bias,
    float* __restrict__ Cf, short* __restrict__ Cb,
    int M, int N, int K, int splitcol) {
  __shared__ __attribute__((aligned(16))) short As[128 * 32];
  __shared__ __attribute__((aligned(16))) short Bs[128 * 32];

  const int tid = threadIdx.x;
  const int wave = tid >> 6, lane = tid & 63;
  const int lm = lane & 15, lq = lane >> 4;
  const int row0 = blockIdx.y * 128, col0 = blockIdx.x * 128;
  const int wr = (wave >> 1) * 64, wc = (wave & 1) * 64;

  const short* A = (col0 < splitcol) ? A0 : A1;
  const short* ag = A + (size_t)(row0 + wave * 32 + (lane >> 2)) * K + (lane & 3) * 8;
  const short* bg = Bt + (size_t)(col0 + wave * 32 + (lane >> 2)) * K + (lane & 3) * 8;
  short* asl = &As[wave * 32 * 32];
  short* bsl = &Bs[wave * 32 * 32];

  f32x4 acc[4][4];
#pragma unroll
  for (int i = 0; i < 4; i++)
#pragma unroll
    for (int j = 0; j < 4; j++) acc[i][j] = (f32x4){0.f, 0.f, 0.f, 0.f};

  for (int k0 = 0; k0 < K; k0 += 32) {
    load_lds16(ag + k0, asl);
    load_lds16(ag + (size_t)16 * K + k0, asl + 16 * 32);
    load_lds16(bg + k0, bsl);
    load_lds16(bg + (size_t)16 * K + k0, bsl + 16 * 32);
    __syncthreads();

    short8 af[4], bfr[4];
#pragma unroll
    for (int i = 0; i < 4; i++)
      af[i] = *(const short8*)(&As[(wr + 16 * i + lm) * 32 + lq * 8]);
#pragma unroll
    for (int j = 0; j < 4; j++)
      bfr[j] = *(const short8*)(&Bs[(wc + 16 * j + lm) * 32 + lq * 8]);
#pragma unroll
    for (int i = 0; i < 4; i++)
#pragma unroll
      for (int j = 0; j < 4; j++) acc[i][j] = mfma16(af[i], bfr[j], acc[i][j]);
    __syncthreads();
  }

#pragma unroll
  for (int i = 0; i < 4; i++) {
#pragma unroll
    for (int j = 0; j < 4; j++) {
      const int col = col0 + wc + 16 * j + lm;
      const float bs = bias[col];
#pragma unroll
      for (int r = 0; r < 4; r++) {
        const int row = row0 + wr + 16 * i + lq * 4 + r;
        float v = acc[i][j][r] + bs;
        if (RELU) v = fmaxf(v, 0.f);
        if (OUT_BF16)
          Cb[(size_t)row * N + col] = f2bs(v);
        else
          Cf[(size_t)row * N + col] = v;
      }
    }
  }
}

// ---------------------------------------------------------------------------
// Split-K GEMM 128x128: block z covers K range [z*Kslice, (z+1)*Kslice),
// writes f32 partial (no bias) to Cf + z*M*N. No atomics.
// ---------------------------------------------------------------------------
__global__ __launch_bounds__(256) void gemm_bt_part(
    const short* __restrict__ A, const short* __restrict__ Bt,
    float* __restrict__ Cf, int M, int N, int K, int Kslice) {
  __shared__ __attribute__((aligned(16))) short As[128 * 32];
  __shared__ __attribute__((aligned(16))) short Bs[128 * 32];

  const int tid = threadIdx.x;
  const int wave = tid >> 6, lane = tid & 63;
  const int lm = lane & 15, lq = lane >> 4;
  const int row0 = blockIdx.y * 128, col0 = blockIdx.x * 128;
  const int kbase = blockIdx.z * Kslice;
  const int wr = (wave >> 1) * 64, wc = (wave & 1) * 64;
  Cf += (size_t)blockIdx.z * M * N;

  const short* ag = A + (size_t)(row0 + wave * 32 + (lane >> 2)) * K + (lane & 3) * 8;
  const short* bg = Bt + (size_t)(col0 + wave * 32 + (lane >> 2)) * K + (lane & 3) * 8;
  short* asl = &As[wave * 32 * 32];
  short* bsl = &Bs[wave * 32 * 32];

  f32x4 acc[4][4];
#pragma unroll
  for (int i = 0; i < 4; i++)
#pragma unroll
    for (int j = 0; j < 4; j++) acc[i][j] = (f32x4){0.f, 0.f, 0.f, 0.f};

  for (int k0 = kbase; k0 < kbase + Kslice; k0 += 32) {
    load_lds16(ag + k0, asl);
    load_lds16(ag + (size_t)16 * K + k0, asl + 16 * 32);
    load_lds16(bg + k0, bsl);
    load_lds16(bg + (size_t)16 * K + k0, bsl + 16 * 32);
    __syncthreads();

    short8 af[4], bfr[4];
#pragma unroll
    for (int i = 0; i < 4; i++)
      af[i] = *(const short8*)(&As[(wr + 16 * i + lm) * 32 + lq * 8]);
#pragma unroll
    for (int j = 0; j < 4; j++)
      bfr[j] = *(const short8*)(&Bs[(wc + 16 * j + lm) * 32 + lq * 8]);
#pragma unroll
    for (int i = 0; i < 4; i++)
#pragma unroll
      for (int j = 0; j < 4; j++) acc[i][j] = mfma16(af[i], bfr[j], acc[i][j]);
    __syncthreads();
  }

#pragma unroll
  for (int i = 0; i < 4; i++) {
#pragma unroll
    for (int j = 0; j < 4; j++) {
      const int col = col0 + wc + 16 * j + lm;
#pragma unroll
      for (int r = 0; r < 4; r++) {
        const int row = row0 + wr + 16 * i + lq * 4 + r;
        Cf[(size_t)row * N + col] = acc[i][j][r];
      }
    }
  }
}

// ---------------------------------------------------------------------------
// Fused attention, S^T form, non-online softmax, NO split-K, KVBLK=32.
//
// R8: R7's proven loop (32+32 VGPR, 16 KB LDS, no spill) with NSPLIT=1:
// each block covers ALL 2048 keys (64 iters), so l is complete per block
// -> the divide + bf16 convert fold into the epilogue and combine_ctx is
// DELETED (8 us + 33 MB read + 25 MB write). Occupancy evidence (R5 16
// waves = R7 32 waves = ~94 us) says 2 blocks/CU (16 waves) holds the
// floor; per-CU block-iterations unchanged at 128. attn now writes bf16
// ctx directly (WRITE 37 -> ~9 MB). Grid (NHEAD, S_LEN/128, BATCH) = 512
// blocks x 512 thr = exactly 2/CU.
// ---------------------------------------------------------------------------
__global__ __launch_bounds__(512, 8) void attn_kernel(
    const short* __restrict__ QKV,   // [NTOK][3072]: Q*0.125 | K | V
    const short* __restrict__ VT,    // [DMODEL][NTOK]
    const short* __restrict__ corrb, // [B][S][S] bf16
    short* __restrict__ ctx) {       // [NTOK][DMODEL] bf16 out
  const int h = blockIdx.x, qtile = blockIdx.y;
  const int b = blockIdx.z;
  const int tid = threadIdx.x;
  const int wave = tid >> 6, lane = tid & 63;
  const int lm = lane & 15, lq = lane >> 4;
  const int qb = qtile * 128 + wave * 16;
  const int fx = lm & 7;         // K-tile read swizzle key (8 units/row)
  const int fy = (lm >> 1) & 3;  // V/P read swizzle key (4 units/row)

  __shared__ __attribute__((aligned(16))) short Ks[32 * 64];      // 4 KB
  __shared__ __attribute__((aligned(16))) short Vs[64 * 32];      // 4 KB
  __shared__ __attribute__((aligned(16))) short Ps[8 * 16 * 32];  // 8 KB

  const short* q0 = QKV + (size_t)(b * S_LEN + qb + lm) * QKVLD + h * DHEAD;
  const short8 qA0 = *(const short8*)(q0 + lq * 8);
  const short8 qA1 = *(const short8*)(q0 + lq * 8 + 32);

  f32x4 oA[4];
#pragma unroll
  for (int t = 0; t < 4; t++) oA[t] = (f32x4){0.f, 0.f, 0.f, 0.f};
  f32x4 lacc = (f32x4){0.f, 0.f, 0.f, 0.f};

  const short* c0 = corrb + (size_t)(b * S_LEN + qb + lm) * S_LEN;

  // --- staging: waves 0-3 stage K (32 rows x 8 units), waves 4-7 stage V
  // (64 rows x 4 units); 256 threads each, one int4 per tile. Wave-uniform
  // branch. Swizzle on the LDS write side; read side uses fx/fy keys.
  const int st = tid & 255;
  const bool isK = tid < 256;
  short* sdst;
  const short* sgp;
  size_t sstep;
  if (isK) {
    const int krow = st >> 3, ku = st & 7;
    sdst = &Ks[krow * 64 + ((ku ^ (krow & 7)) * 8)];
    sgp = QKV + (size_t)(b * S_LEN + krow) * QKVLD + DMODEL + h * DHEAD + ku * 8;
    sstep = (size_t)32 * QKVLD;
  } else {
    const int vrow = st >> 2, vu = st & 3;
    sdst = &Vs[vrow * 32 + ((vu ^ ((vrow >> 1) & 3)) * 8)];
    sgp = VT + (size_t)(h * DHEAD + vrow) * NTOK + b * S_LEN + vu * 8;
    sstep = 32;
  }

  for (int kt = 0; kt < S_LEN; kt += 32) {
    *(int4*)sdst = *(const int4*)sgp;
    sgp += sstep;
    __syncthreads();

    // --- scores S^T (swizzled K frag reads): 32 keys x 16 queries
    f32x4 sv[2];
    __builtin_amdgcn_s_setprio(1);
#pragma unroll
    for (int t = 0; t < 2; t++) {
      const int rb = (t * 16 + lm) * 64;
      const short8 kf0 = *(const short8*)(&Ks[rb + (lq ^ fx) * 8]);
      const short8 kf1 = *(const short8*)(&Ks[rb + ((lq + 4) ^ fx) * 8]);
      f32x4 a = (f32x4){0.f, 0.f, 0.f, 0.f};
      a = mfma16(kf0, qA0, a);
      a = mfma16(kf1, qA1, a);
      sv[t] = a;
    }
    __builtin_amdgcn_s_setprio(0);

    // --- exp(s + corr), accumulate row sums, pack P (swizzled, wave-private)
#pragma unroll
    for (int t = 0; t < 2; t++) {
      const short4v cr = *(const short4v*)(c0 + kt + t * 16 + lq * 4);
#pragma unroll
      for (int r = 0; r < 4; r++)
        sv[t][r] = __expf(sv[t][r] + bs2f(cr[r]));
      lacc += sv[t];
      short4v pA = {f2bs(sv[t][0]), f2bs(sv[t][1]), f2bs(sv[t][2]), f2bs(sv[t][3])};
      const int pu = ((2 * t + (lq >> 1)) ^ fy) * 8 + (lq & 1) * 4;
      *(short4v*)(&Ps[wave * 512 + lm * 32 + pu]) = pA;
    }

    // --- PV (swizzled P and V frag reads; K-contraction = 32 tokens)
    const short8 pA0 = *(const short8*)(&Ps[wave * 512 + lm * 32 + (lq ^ fy) * 8]);
    __builtin_amdgcn_s_setprio(1);
#pragma unroll
    for (int t = 0; t < 4; t++) {
      const int vrb = (t * 16 + lm) * 32;
      const short8 vf0 = *(const short8*)(&Vs[vrb + (lq ^ fy) * 8]);
      oA[t] = mfma16(vf0, pA0, oA[t]);
    }
    __builtin_amdgcn_s_setprio(0);
    __syncthreads();
  }

  // --- epilogue: full softmax denominator, divide, bf16 out (no combine)
  float lA = lacc[0] + lacc[1] + lacc[2] + lacc[3];
  lA += __shfl_xor(lA, 16);
  lA += __shfl_xor(lA, 32);
  const float inv = 1.0f / lA;
  short* op = ctx + (size_t)(b * S_LEN + qb + lm) * DMODEL + h * DHEAD;
#pragma unroll
  for (int t = 0; t < 4; t++) {
    short4v ov = {f2bs(oA[t][0] * inv), f2bs(oA[t][1] * inv),
                  f2bs(oA[t][2] * inv), f2bs(oA[t][3] * inv)};
    *(short4v*)(op + t * 16 + lq * 4) = ov;
  }
}

// ---------------------------------------------------------------------------
// Residual + 2 GEMM partials + bias + LayerNorm. One block per token row.
// v = xa + p0 + p1 + bias; out = LN(v)*g + be
// ---------------------------------------------------------------------------
__global__ __launch_bounds__(256) void residual_ln3(
    const float* __restrict__ xa, const float* __restrict__ p0,
    const float* __restrict__ p1, const float* __restrict__ bias,
    const float* __restrict__ g, const float* __restrict__ be,
    float* __restrict__ outf, short* __restrict__ outb) {
  const int row = blockIdx.x;
  const int t = threadIdx.x;
  const size_t base = (size_t)row * DMODEL + t * 4;
  float4 a = *(const float4*)(xa + base);
  f32x4 q0 = *(const f32x4*)(p0 + base);
  f32x4 q1 = *(const f32x4*)(p1 + base);
  f32x4 bb = *(const f32x4*)(bias + t * 4);
  const float v0 = a.x + q0[0] + q1[0] + bb[0];
  const float v1 = a.y + q0[1] + q1[1] + bb[1];
  const float v2 = a.z + q0[2] + q1[2] + bb[2];
  const float v3 = a.w + q0[3] + q1[3] + bb[3];
  float sum = v0 + v1 + v2 + v3;
  float sq = v0 * v0 + v1 * v1 + v2 * v2 + v3 * v3;
#pragma unroll
  for (int off = 1; off < 64; off <<= 1) {
    sum += __shfl_xor(sum, off);
    sq += __shfl_xor(sq, off);
  }
  __shared__ float ssum[4], ssq[4];
  const int wave = t >> 6;
  if ((t & 63) == 0) { ssum[wave] = sum; ssq[wave] = sq; }
  __syncthreads();
  sum = ssum[0] + ssum[1] + ssum[2] + ssum[3];
  sq = ssq[0] + ssq[1] + ssq[2] + ssq[3];
  const float mean = sum * (1.0f / DMODEL);
  const float var = sq * (1.0f / DMODEL) - mean * mean;
  const float rstd = rsqrtf(var + 1e-5f);
  float4 gv = *(const float4*)(g + t * 4);
  float4 bv = *(const float4*)(be + t * 4);
  const float o0 = (v0 - mean) * rstd * gv.x + bv.x;
  const float o1 = (v1 - mean) * rstd * gv.y + bv.y;
  const float o2 = (v2 - mean) * rstd * gv.z + bv.z;
  const float o3 = (v3 - mean) * rstd * gv.w + bv.w;
  if (outf) {
    float4 ov = {o0, o1, o2, o3};
    *(float4*)(outf + base) = ov;
  }
  if (outb) {
    short4v ob = {f2bs(o0), f2bs(o1), f2bs(o2), f2bs(o3)};
    *(short4v*)(outb + base) = ob;
  }
}

// ---------------------------------------------------------------------------
extern "C" void kernel_launch(void* const* d_in, const int* in_sizes, int n_in,
                              void* d_out, int out_size, void* d_ws, size_t ws_size,
                              hipStream_t stream) {
  const float* src = (const float*)d_in[0];
  const float* corr = (const float*)d_in[1];
  const float* pos = (const float*)d_in[2];
  const float* Wq = (const float*)d_in[3];
  const float* bq = (const float*)d_in[4];
  const float* Wk = (const float*)d_in[5];
  const float* bk = (const float*)d_in[6];
  const float* Wv = (const float*)d_in[7];
  const float* bv = (const float*)d_in[8];
  const float* Wo = (const float*)d_in[9];
  const float* bo = (const float*)d_in[10];
  const float* W1 = (const float*)d_in[11];
  const float* b1 = (const float*)d_in[12];
  const float* W2 = (const float*)d_in[13];
  const float* b2 = (const float*)d_in[14];
  const float* g1 = (const float*)d_in[15];
  const float* be1 = (const float*)d_in[16];
  const float* g2 = (const float*)d_in[17];
  const float* be2 = (const float*)d_in[18];
  float* out = (float*)d_out;

  char* ws = (char*)d_ws;
  size_t off = 0;
  auto alloc = [&](size_t bytes) {
    char* p = ws + off;
    off += (bytes + 255) & ~(size_t)255;
    return p;
  };
  short* WqkvT = (short*)alloc((size_t)QKVLD * DMODEL * 2);  // [3072][1024]
  short* WoT = (short*)alloc((size_t)DMODEL * DMODEL * 2);
  short* W1T = (short*)alloc((size_t)DFF * DMODEL * 2);
  short* W2T = (short*)alloc((size_t)DMODEL * DFF * 2);
  float* bqkv = (float*)alloc((size_t)QKVLD * 4);
  short* qkb = (short*)alloc((size_t)NTOK * DMODEL * 2);
  short* srcb = (short*)alloc((size_t)NTOK * DMODEL * 2);
  short* QKVb = (short*)alloc((size_t)NTOK * QKVLD * 2);   // fused Q|K|V (24 MB)
  short* VTt = (short*)alloc((size_t)DMODEL * NTOK * 2);
  short* corrb = (short*)alloc((size_t)BATCH * S_LEN * S_LEN * 2);  // 16.8 MB
  short* ctxb = (short*)alloc((size_t)NTOK * DMODEL * 2);
  float* Pp = (float*)alloc((size_t)2 * NTOK * DMODEL * 4);  // split-K partials
  short* Hb = (short*)alloc((size_t)NTOK * DFF * 2);         // FFN hidden
  float* x1f = (float*)alloc((size_t)NTOK * DMODEL * 4);
  short* x1b = (short*)alloc((size_t)NTOK * DMODEL * 2);

  // 1) all static prep (6 transposes + bias concat) in one dispatch
  prep_static<<<12300, dim3(32, 8), 0, stream>>>(
      Wq, Wk, Wv, Wo, W1, W2, bq, bk, bv, WqkvT, WoT, W1T, W2T, bqkv);

  // 2) token + corr prep in one dispatch
  prep_inputs<<<12288, 256, 0, stream>>>(src, pos, corr, qkb, srcb, corrb);

  // 3) fused Q|K|V projection: cols<2048 use qkb, cols>=2048 use srcb
  gemm_bt<0, 1><<<dim3(QKVLD / 128, NTOK / 128), 256, 0, stream>>>(
      qkb, srcb, WqkvT, bqkv, nullptr, QKVb, NTOK, QKVLD, DMODEL, 2048);

  // 4) V^T for attention PV a-operand (V = cols 2048.. of QKVb)
  transpose_bf16<<<dim3(DMODEL / 64, NTOK / 64), 256, 0, stream>>>(
      QKVb + 2048, VTt, NTOK, QKVLD);

  // 5) attention, NO split-K (512 blocks x 512 thr); writes ctxb directly
  attn_kernel<<<dim3(NHEAD, S_LEN / 128, BATCH), 512, 0, stream>>>(
      QKVb, VTt, corrb, ctxb);

  // 6) output projection: split-K x2 partials, summed in LN1
  gemm_bt_part<<<dim3(DMODEL / 128, NTOK / 128, 2), 256, 0, stream>>>(
      ctxb, WoT, Pp, NTOK, DMODEL, DMODEL, DMODEL / 2);

  // 7) LN1: x1 = LN(src + P0 + P1 + bo)
  residual_ln3<<<NTOK, 256, 0, stream>>>(src, Pp, Pp + (size_t)NTOK * DMODEL,
                                         bo, g1, be1, x1f, x1b);

  // 8) FFN1 (128x128, 1024 blocks)
  gemm_bt<1, 1><<<dim3(DFF / 128, NTOK / 128), 256, 0, stream>>>(
      x1b, x1b, W1T, b1, nullptr, Hb, NTOK, DFF, DMODEL, 1 << 30);

  // 9) FFN2: split-K x2 partials, summed in LN2
  gemm_bt_part<<<dim3(DMODEL / 128, NTOK / 128, 2), 256, 0, stream>>>(
      Hb, W2T, Pp, NTOK, DMODEL, DFF, DFF / 2);

  // 10) LN2 -> output
  residual_ln3<<<NTOK, 256, 0, stream>>>(x1f, Pp, Pp + (size_t)NTOK * DMODEL,
                                         b2, g2, be2, out, nullptr);
}

// Round 9
// 478.188 us; speedup vs baseline: 1.8412x; 1.0051x over previous
//
#include <hip/hip_runtime.h>
#include <hip/hip_bf16.h>

#define S_LEN  2048
#define BATCH  2
#define DMODEL 1024
#define NHEAD  16
#define DHEAD  64
#define DFF    4096
#define NTOK   (BATCH * S_LEN)
#define QKVLD  3072   // fused Q|K|V output row stride
#define NSPLIT 2      // attention split-K factor

typedef __attribute__((ext_vector_type(8))) short short8;
typedef __attribute__((ext_vector_type(4))) short short4v;
typedef __attribute__((ext_vector_type(4))) float f32x4;

__device__ __forceinline__ short f2bs(float f) {
  __hip_bfloat16 h = __float2bfloat16(f);
  short s;
  __builtin_memcpy(&s, &h, sizeof(short));
  return s;
}

__device__ __forceinline__ float bs2f(short s) {
  unsigned u = ((unsigned)(unsigned short)s) << 16;
  float f;
  __builtin_memcpy(&f, &u, sizeof(float));
  return f;
}

__device__ __forceinline__ f32x4 mfma16(short8 a, short8 b, f32x4 c) {
  return __builtin_amdgcn_mfma_f32_16x16x32_bf16(a, b, c, 0, 0, 0);
}

// async global->LDS, 16B per lane; LDS dest = wave-uniform base + lane*16
__device__ __forceinline__ void load_lds16(const short* g, short* l) {
  __builtin_amdgcn_global_load_lds(
      (const __attribute__((address_space(1))) void*)g,
      (__attribute__((address_space(3))) void*)l, 16, 0, 0);
}

// ---------------------------------------------------------------------------
// prep_static: ALL weight transposes + bias concat in ONE dispatch.
//   [    0, 1024): Wq -> WqkvT[0..]        (scale 0.125)
//   [ 1024, 2048): Wk -> WqkvT[1M..]
//   [ 2048, 3072): Wv -> WqkvT[2M..]
//   [ 3072, 4096): Wo -> WoT
//   [ 4096, 8192): W1 (1024x4096) -> W1T
//   [ 8192,12288): W2 (4096x1024) -> W2T
//   [12288,12300): bqkv concat (bq*0.125 | bk | bv)
// ---------------------------------------------------------------------------
__global__ void prep_static(
    const float* __restrict__ Wq, const float* __restrict__ Wk,
    const float* __restrict__ Wv, const float* __restrict__ Wo,
    const float* __restrict__ W1, const float* __restrict__ W2,
    const float* __restrict__ bq, const float* __restrict__ bk,
    const float* __restrict__ bv,
    short* __restrict__ WqkvT, short* __restrict__ WoT,
    short* __restrict__ W1T, short* __restrict__ W2T,
    float* __restrict__ bqkv) {
  const int gid = blockIdx.x;
  const int tx = threadIdx.x, ty = threadIdx.y;  // 32 x 8

  if (gid >= 12288) {  // bias concat
    const int i = (gid - 12288) * 256 + ty * 32 + tx;
    float v;
    if (i < DMODEL) v = bq[i] * 0.125f;
    else if (i < 2 * DMODEL) v = bk[i - DMODEL];
    else v = bv[i - 2 * DMODEL];
    bqkv[i] = v;
    return;
  }

  const float* in;
  short* out;
  int R, C, t;
  float scale = 1.0f;
  if (gid < 4096) {
    t = gid & 1023;
    R = C = 1024;
    if (gid < 1024)      { in = Wq; out = WqkvT;                 scale = 0.125f; }
    else if (gid < 2048) { in = Wk; out = WqkvT + 1024 * 1024; }
    else if (gid < 3072) { in = Wv; out = WqkvT + 2 * 1024 * 1024; }
    else                 { in = Wo; out = WoT; }
  } else if (gid < 8192) {
    t = gid - 4096; in = W1; out = W1T; R = 1024; C = 4096;
  } else {
    t = gid - 8192; in = W2; out = W2T; R = 4096; C = 1024;
  }
  const int tpr = C >> 5;  // tiles per row of C
  const int c0 = (t % tpr) * 32, r0 = (t / tpr) * 32;

  __shared__ float tile[32][33];
#pragma unroll
  for (int i = 0; i < 32; i += 8)
    tile[ty + i][tx] = in[(size_t)(r0 + ty + i) * C + c0 + tx];
  __syncthreads();
#pragma unroll
  for (int i = 0; i < 32; i += 8)
    out[(size_t)(c0 + ty + i) * R + r0 + tx] = f2bs(tile[tx][ty + i] * scale);
}

// ---------------------------------------------------------------------------
// prep_inputs: tokens (qkb/srcb) + corr->bf16 in ONE dispatch.
// ---------------------------------------------------------------------------
__global__ void prep_inputs(const float* __restrict__ src, const float* __restrict__ pos,
                            const float* __restrict__ corr,
                            short* __restrict__ qkb, short* __restrict__ srcb,
                            short* __restrict__ corrb) {
  const int gid = blockIdx.x;
  if (gid < 4096) {
    const int i = gid * 1024 + threadIdx.x * 4;
    float4 s = *(const float4*)(src + i);
    float4 p = *(const float4*)(pos + i);
    short4v q4 = {f2bs(s.x + p.x), f2bs(s.y + p.y), f2bs(s.z + p.z), f2bs(s.w + p.w)};
    short4v s4 = {f2bs(s.x), f2bs(s.y), f2bs(s.z), f2bs(s.w)};
    *(short4v*)(qkb + i) = q4;
    *(short4v*)(srcb + i) = s4;
  } else {
    const size_t i = ((size_t)(gid - 4096)) * 1024 + threadIdx.x * 4;
    float4 c = *(const float4*)(corr + i);
    short4v o = {f2bs(c.x), f2bs(c.y), f2bs(c.z), f2bs(c.w)};
    *(short4v*)(corrb + i) = o;
  }
}

// ---------------------------------------------------------------------------
// bf16 transpose: in [R][LDin] -> out [C][R], 64x64 tiles
// ---------------------------------------------------------------------------
__global__ __launch_bounds__(256) void transpose_bf16(
    const short* __restrict__ in, short* __restrict__ out, int R, int LDin) {
  __shared__ __attribute__((aligned(16))) short tile[64][72];
  const int c0 = blockIdx.x * 64, r0 = blockIdx.y * 64;
#pragma unroll
  for (int i = 0; i < 2; i++) {
    const int idx = threadIdx.x + 256 * i;
    const int rr = idx >> 3, cc8 = (idx & 7) * 8;
    *(int4*)(&tile[rr][cc8]) = *(const int4*)(in + (size_t)(r0 + rr) * LDin + c0 + cc8);
  }
  __syncthreads();
#pragma unroll
  for (int i = 0; i < 2; i++) {
    const int idx = threadIdx.x + 256 * i;
    const int rr = idx >> 3, cc8 = (idx & 7) * 8;
    short8 v;
#pragma unroll
    for (int j = 0; j < 8; j++) v[j] = tile[cc8 + j][rr];
    *(short8*)(out + (size_t)(c0 + rr) * R + r0 + cc8) = v;
  }
}

// ---------------------------------------------------------------------------
// GEMM 128x128 (m97-style), dual-A: column blocks with col0 < splitcol read
// A0, others A1 (for fused QKV: Q/K from src+pos, V from src).
// ---------------------------------------------------------------------------
template <int RELU, int OUT_BF16>
__global__ __launch_bounds__(256) void gemm_bt(
    const short* __restrict__ A0, const short* __restrict__ A1,
    const short* __restrict__ Bt, const float* __restrict__ bias,
    float* __restrict__ Cf, short* __restrict__ Cb,
    int M, int N, int K, int splitcol) {
  __shared__ __attribute__((aligned(16))) short As[128 * 32];
  __shared__ __attribute__((aligned(16))) short Bs[128 * 32];

  const int tid = threadIdx.x;
  const int wave = tid >> 6, lane = tid & 63;
  const int lm = lane & 15, lq = lane >> 4;
  const int row0 = blockIdx.y * 128, col0 = blockIdx.x * 128;
  const int wr = (wave >> 1) * 64, wc = (wave & 1) * 64;

  const short* A = (col0 < splitcol) ? A0 : A1;
  const short* ag = A + (size_t)(row0 + wave * 32 + (lane >> 2)) * K + (lane & 3) * 8;
  const short* bg = Bt + (size_t)(col0 + wave * 32 + (lane >> 2)) * K + (lane & 3) * 8;
  short* asl = &As[wave * 32 * 32];
  short* bsl = &Bs[wave * 32 * 32];

  f32x4 acc[4][4];
#pragma unroll
  for (int i = 0; i < 4; i++)
#pragma unroll
    for (int j = 0; j < 4; j++) acc[i][j] = (f32x4){0.f, 0.f, 0.f, 0.f};

  for (int k0 = 0; k0 < K; k0 += 32) {
    load_lds16(ag + k0, asl);
    load_lds16(ag + (size_t)16 * K + k0, asl + 16 * 32);
    load_lds16(bg + k0, bsl);
    load_lds16(bg + (size_t)16 * K + k0, bsl + 16 * 32);
    __syncthreads();

    short8 af[4], bfr[4];
#pragma unroll
    for (int i = 0; i < 4; i++)
      af[i] = *(const short8*)(&As[(wr + 16 * i + lm) * 32 + lq * 8]);
#pragma unroll
    for (int j = 0; j < 4; j++)
      bfr[j] = *(const short8*)(&Bs[(wc + 16 * j + lm) * 32 + lq * 8]);
#pragma unroll
    for (int i = 0; i < 4; i++)
#pragma unroll
      for (int j = 0; j < 4; j++) acc[i][j] = mfma16(af[i], bfr[j], acc[i][j]);
    __syncthreads();
  }

#pragma unroll
  for (int i = 0; i < 4; i++) {
#pragma unroll
    for (int j = 0; j < 4; j++) {
      const int col = col0 + wc + 16 * j + lm;
      const float bs = bias[col];
#pragma unroll
      for (int r = 0; r < 4; r++) {
        const int row = row0 + wr + 16 * i + lq * 4 + r;
        float v = acc[i][j][r] + bs;
        if (RELU) v = fmaxf(v, 0.f);
        if (OUT_BF16)
          Cb[(size_t)row * N + col] = f2bs(v);
        else
          Cf[(size_t)row * N + col] = v;
      }
    }
  }
}

// ---------------------------------------------------------------------------
// Split-K GEMM 128x128: block z covers K range [z*Kslice, (z+1)*Kslice),
// writes f32 partial (no bias) to Cf + z*M*N. No atomics.
// ---------------------------------------------------------------------------
__global__ __launch_bounds__(256) void gemm_bt_part(
    const short* __restrict__ A, const short* __restrict__ Bt,
    float* __restrict__ Cf, int M, int N, int K, int Kslice) {
  __shared__ __attribute__((aligned(16))) short As[128 * 32];
  __shared__ __attribute__((aligned(16))) short Bs[128 * 32];

  const int tid = threadIdx.x;
  const int wave = tid >> 6, lane = tid & 63;
  const int lm = lane & 15, lq = lane >> 4;
  const int row0 = blockIdx.y * 128, col0 = blockIdx.x * 128;
  const int kbase = blockIdx.z * Kslice;
  const int wr = (wave >> 1) * 64, wc = (wave & 1) * 64;
  Cf += (size_t)blockIdx.z * M * N;

  const short* ag = A + (size_t)(row0 + wave * 32 + (lane >> 2)) * K + (lane & 3) * 8;
  const short* bg = Bt + (size_t)(col0 + wave * 32 + (lane >> 2)) * K + (lane & 3) * 8;
  short* asl = &As[wave * 32 * 32];
  short* bsl = &Bs[wave * 32 * 32];

  f32x4 acc[4][4];
#pragma unroll
  for (int i = 0; i < 4; i++)
#pragma unroll
    for (int j = 0; j < 4; j++) acc[i][j] = (f32x4){0.f, 0.f, 0.f, 0.f};

  for (int k0 = kbase; k0 < kbase + Kslice; k0 += 32) {
    load_lds16(ag + k0, asl);
    load_lds16(ag + (size_t)16 * K + k0, asl + 16 * 32);
    load_lds16(bg + k0, bsl);
    load_lds16(bg + (size_t)16 * K + k0, bsl + 16 * 32);
    __syncthreads();

    short8 af[4], bfr[4];
#pragma unroll
    for (int i = 0; i < 4; i++)
      af[i] = *(const short8*)(&As[(wr + 16 * i + lm) * 32 + lq * 8]);
#pragma unroll
    for (int j = 0; j < 4; j++)
      bfr[j] = *(const short8*)(&Bs[(wc + 16 * j + lm) * 32 + lq * 8]);
#pragma unroll
    for (int i = 0; i < 4; i++)
#pragma unroll
      for (int j = 0; j < 4; j++) acc[i][j] = mfma16(af[i], bfr[j], acc[i][j]);
    __syncthreads();
  }

#pragma unroll
  for (int i = 0; i < 4; i++) {
#pragma unroll
    for (int j = 0; j < 4; j++) {
      const int col = col0 + wc + 16 * j + lm;
#pragma unroll
      for (int r = 0; r < 4; r++) {
        const int row = row0 + wr + 16 * i + lq * 4 + r;
        Cf[(size_t)row * N + col] = acc[i][j][r];
      }
    }
  }
}

// ---------------------------------------------------------------------------
// Fused attention, S^T form, non-online softmax, split-K x2, KVBLK=32.
//
// R9: probe 8 INDEPENDENT blocks/CU. Evidence: attn time tracks independent
// barrier-groups per CU, not waves (2 blk -> 114 us [R8], 4 blk -> 94 us
// [R5/R7 at both 16 and 32 waves]). Config: 256-thread blocks (4 waves x
// 16 q-rows = 64 q-rows/block), NSPLIT=2 -> grid (16, 32, 4) = 2048 blocks
// = 8/CU. LDS 12 KB (Ks 4K + Vs 4K + Ps[4][16][32] 4K) x 8 = 96 KB. Per-
// wave registers identical to R7's proven 32+32 fit (each thread now does
// one K AND one V staging load: +4 addr regs, still <= 64 total).
// Spill check: WRITE_SIZE >> 40 MB. Saturation check: attn ~94 us means
// the 4-block floor is per-iteration latency, pivot to GEMM ladder.
// ---------------------------------------------------------------------------
__global__ __launch_bounds__(256, 8) void attn_kernel(
    const short* __restrict__ QKV,   // [NTOK][3072]: Q*0.125 | K | V
    const short* __restrict__ VT,    // [DMODEL][NTOK]
    const short* __restrict__ corrb, // [B][S][S] bf16
    float* __restrict__ Op,          // [NSPLIT][NTOK][DMODEL] partial numerators
    float* __restrict__ lp) {        // [NSPLIT][NTOK][NHEAD] partial denominators
  const int h = blockIdx.x, qtile = blockIdx.y;
  const int b = blockIdx.z >> 1, split = blockIdx.z & 1;
  const int koff = split * (S_LEN / NSPLIT);
  const int tid = threadIdx.x;
  const int wave = tid >> 6, lane = tid & 63;
  const int lm = lane & 15, lq = lane >> 4;
  const int qb = qtile * 64 + wave * 16;
  const int fx = lm & 7;         // K-tile read swizzle key (8 units/row)
  const int fy = (lm >> 1) & 3;  // V/P read swizzle key (4 units/row)

  __shared__ __attribute__((aligned(16))) short Ks[32 * 64];      // 4 KB
  __shared__ __attribute__((aligned(16))) short Vs[64 * 32];      // 4 KB
  __shared__ __attribute__((aligned(16))) short Ps[4 * 16 * 32];  // 4 KB

  const short* q0 = QKV + (size_t)(b * S_LEN + qb + lm) * QKVLD + h * DHEAD;
  const short8 qA0 = *(const short8*)(q0 + lq * 8);
  const short8 qA1 = *(const short8*)(q0 + lq * 8 + 32);

  f32x4 oA[4];
#pragma unroll
  for (int t = 0; t < 4; t++) oA[t] = (f32x4){0.f, 0.f, 0.f, 0.f};
  f32x4 lacc = (f32x4){0.f, 0.f, 0.f, 0.f};

  const short* c0 = corrb + (size_t)(b * S_LEN + qb + lm) * S_LEN;

  // --- staging: every thread stages ONE K int4 and ONE V int4 per tile.
  // K: 32 rows x 8 units (krow=tid>>3, ku=tid&7), phys = ku^(krow&7).
  // V: 64 rows x 4 units (vrow=tid>>2, vu=tid&3), phys = vu^((vrow>>1)&3).
  const int krow = tid >> 3, ku = tid & 7;
  short* kdst = &Ks[krow * 64 + ((ku ^ (krow & 7)) * 8)];
  const short* kgp = QKV + (size_t)(b * S_LEN + koff + krow) * QKVLD + DMODEL +
                     h * DHEAD + ku * 8;
  const int vrow = tid >> 2, vu = tid & 3;
  short* vdst = &Vs[vrow * 32 + ((vu ^ ((vrow >> 1) & 3)) * 8)];
  const short* vgp = VT + (size_t)(h * DHEAD + vrow) * NTOK + b * S_LEN + koff + vu * 8;

  for (int kt = koff; kt < koff + S_LEN / NSPLIT; kt += 32) {
    *(int4*)kdst = *(const int4*)kgp;
    *(int4*)vdst = *(const int4*)vgp;
    kgp += (size_t)32 * QKVLD;
    vgp += 32;
    __syncthreads();

    // --- scores S^T (swizzled K frag reads): 32 keys x 16 queries
    f32x4 sv[2];
    __builtin_amdgcn_s_setprio(1);
#pragma unroll
    for (int t = 0; t < 2; t++) {
      const int rb = (t * 16 + lm) * 64;
      const short8 kf0 = *(const short8*)(&Ks[rb + (lq ^ fx) * 8]);
      const short8 kf1 = *(const short8*)(&Ks[rb + ((lq + 4) ^ fx) * 8]);
      f32x4 a = (f32x4){0.f, 0.f, 0.f, 0.f};
      a = mfma16(kf0, qA0, a);
      a = mfma16(kf1, qA1, a);
      sv[t] = a;
    }
    __builtin_amdgcn_s_setprio(0);

    // --- exp(s + corr), accumulate row sums, pack P (swizzled, wave-private)
#pragma unroll
    for (int t = 0; t < 2; t++) {
      const short4v cr = *(const short4v*)(c0 + kt + t * 16 + lq * 4);
#pragma unroll
      for (int r = 0; r < 4; r++)
        sv[t][r] = __expf(sv[t][r] + bs2f(cr[r]));
      lacc += sv[t];
      short4v pA = {f2bs(sv[t][0]), f2bs(sv[t][1]), f2bs(sv[t][2]), f2bs(sv[t][3])};
      const int pu = ((2 * t + (lq >> 1)) ^ fy) * 8 + (lq & 1) * 4;
      *(short4v*)(&Ps[wave * 512 + lm * 32 + pu]) = pA;
    }

    // --- PV (swizzled P and V frag reads; K-contraction = 32 tokens)
    const short8 pA0 = *(const short8*)(&Ps[wave * 512 + lm * 32 + (lq ^ fy) * 8]);
    __builtin_amdgcn_s_setprio(1);
#pragma unroll
    for (int t = 0; t < 4; t++) {
      const int vrb = (t * 16 + lm) * 32;
      const short8 vf0 = *(const short8*)(&Vs[vrb + (lq ^ fy) * 8]);
      oA[t] = mfma16(vf0, pA0, oA[t]);
    }
    __builtin_amdgcn_s_setprio(0);
    __syncthreads();
  }

  // --- epilogue: partial sums out (no divide)
  float lA = lacc[0] + lacc[1] + lacc[2] + lacc[3];
  lA += __shfl_xor(lA, 16);
  lA += __shfl_xor(lA, 32);
  if (lq == 0)
    lp[((size_t)split * NTOK + b * S_LEN + qb + lm) * NHEAD + h] = lA;
  float* opA = Op + (size_t)split * NTOK * DMODEL +
               (size_t)(b * S_LEN + qb + lm) * DMODEL + h * DHEAD;
#pragma unroll
  for (int t = 0; t < 4; t++)
    *(f32x4*)(opA + t * 16 + lq * 4) = oA[t];
}

// ---------------------------------------------------------------------------
// Combine split-K partials: ctx = (O0+O1)/(l0+l1), bf16
// ---------------------------------------------------------------------------
__global__ __launch_bounds__(256) void combine_ctx(
    const float* __restrict__ Op, const float* __restrict__ lp,
    short* __restrict__ ctx) {
  const size_t idx = ((size_t)blockIdx.x * 256 + threadIdx.x) * 4;
  const int token = (int)(idx >> 10);
  const int d = (int)(idx & 1023);
  const int h = d >> 6;
  f32x4 o = (f32x4){0.f, 0.f, 0.f, 0.f};
  float l = 0.f;
#pragma unroll
  for (int s = 0; s < NSPLIT; s++) {
    o += *(const f32x4*)(Op + (size_t)s * NTOK * DMODEL + idx);
    l += lp[((size_t)s * NTOK + token) * NHEAD + h];
  }
  const float inv = 1.0f / l;
  short4v ov = {f2bs(o[0] * inv), f2bs(o[1] * inv),
                f2bs(o[2] * inv), f2bs(o[3] * inv)};
  *(short4v*)(ctx + idx) = ov;
}

// ---------------------------------------------------------------------------
// Residual + 2 GEMM partials + bias + LayerNorm. One block per token row.
// v = xa + p0 + p1 + bias; out = LN(v)*g + be
// ---------------------------------------------------------------------------
__global__ __launch_bounds__(256) void residual_ln3(
    const float* __restrict__ xa, const float* __restrict__ p0,
    const float* __restrict__ p1, const float* __restrict__ bias,
    const float* __restrict__ g, const float* __restrict__ be,
    float* __restrict__ outf, short* __restrict__ outb) {
  const int row = blockIdx.x;
  const int t = threadIdx.x;
  const size_t base = (size_t)row * DMODEL + t * 4;
  float4 a = *(const float4*)(xa + base);
  f32x4 q0 = *(const f32x4*)(p0 + base);
  f32x4 q1 = *(const f32x4*)(p1 + base);
  f32x4 bb = *(const f32x4*)(bias + t * 4);
  const float v0 = a.x + q0[0] + q1[0] + bb[0];
  const float v1 = a.y + q0[1] + q1[1] + bb[1];
  const float v2 = a.z + q0[2] + q1[2] + bb[2];
  const float v3 = a.w + q0[3] + q1[3] + bb[3];
  float sum = v0 + v1 + v2 + v3;
  float sq = v0 * v0 + v1 * v1 + v2 * v2 + v3 * v3;
#pragma unroll
  for (int off = 1; off < 64; off <<= 1) {
    sum += __shfl_xor(sum, off);
    sq += __shfl_xor(sq, off);
  }
  __shared__ float ssum[4], ssq[4];
  const int wave = t >> 6;
  if ((t & 63) == 0) { ssum[wave] = sum; ssq[wave] = sq; }
  __syncthreads();
  sum = ssum[0] + ssum[1] + ssum[2] + ssum[3];
  sq = ssq[0] + ssq[1] + ssq[2] + ssq[3];
  const float mean = sum * (1.0f / DMODEL);
  const float var = sq * (1.0f / DMODEL) - mean * mean;
  const float rstd = rsqrtf(var + 1e-5f);
  float4 gv = *(const float4*)(g + t * 4);
  float4 bv = *(const float4*)(be + t * 4);
  const float o0 = (v0 - mean) * rstd * gv.x + bv.x;
  const float o1 = (v1 - mean) * rstd * gv.y + bv.y;
  const float o2 = (v2 - mean) * rstd * gv.z + bv.z;
  const float o3 = (v3 - mean) * rstd * gv.w + bv.w;
  if (outf) {
    float4 ov = {o0, o1, o2, o3};
    *(float4*)(outf + base) = ov;
  }
  if (outb) {
    short4v ob = {f2bs(o0), f2bs(o1), f2bs(o2), f2bs(o3)};
    *(short4v*)(outb + base) = ob;
  }
}

// ---------------------------------------------------------------------------
extern "C" void kernel_launch(void* const* d_in, const int* in_sizes, int n_in,
                              void* d_out, int out_size, void* d_ws, size_t ws_size,
                              hipStream_t stream) {
  const float* src = (const float*)d_in[0];
  const float* corr = (const float*)d_in[1];
  const float* pos = (const float*)d_in[2];
  const float* Wq = (const float*)d_in[3];
  const float* bq = (const float*)d_in[4];
  const float* Wk = (const float*)d_in[5];
  const float* bk = (const float*)d_in[6];
  const float* Wv = (const float*)d_in[7];
  const float* bv = (const float*)d_in[8];
  const float* Wo = (const float*)d_in[9];
  const float* bo = (const float*)d_in[10];
  const float* W1 = (const float*)d_in[11];
  const float* b1 = (const float*)d_in[12];
  const float* W2 = (const float*)d_in[13];
  const float* b2 = (const float*)d_in[14];
  const float* g1 = (const float*)d_in[15];
  const float* be1 = (const float*)d_in[16];
  const float* g2 = (const float*)d_in[17];
  const float* be2 = (const float*)d_in[18];
  float* out = (float*)d_out;

  char* ws = (char*)d_ws;
  size_t off = 0;
  auto alloc = [&](size_t bytes) {
    char* p = ws + off;
    off += (bytes + 255) & ~(size_t)255;
    return p;
  };
  short* WqkvT = (short*)alloc((size_t)QKVLD * DMODEL * 2);  // [3072][1024]
  short* WoT = (short*)alloc((size_t)DMODEL * DMODEL * 2);
  short* W1T = (short*)alloc((size_t)DFF * DMODEL * 2);
  short* W2T = (short*)alloc((size_t)DMODEL * DFF * 2);
  float* bqkv = (float*)alloc((size_t)QKVLD * 4);
  short* qkb = (short*)alloc((size_t)NTOK * DMODEL * 2);
  short* srcb = (short*)alloc((size_t)NTOK * DMODEL * 2);
  short* QKVb = (short*)alloc((size_t)NTOK * QKVLD * 2);   // fused Q|K|V (24 MB)
  short* VTt = (short*)alloc((size_t)DMODEL * NTOK * 2);
  short* corrb = (short*)alloc((size_t)BATCH * S_LEN * S_LEN * 2);  // 16.8 MB
  short* ctxb = (short*)alloc((size_t)NTOK * DMODEL * 2);
  float* lp = (float*)alloc((size_t)NSPLIT * NTOK * NHEAD * 4);
  // Pp (33.55 MB) aliased by attn's Op ([2][NTOK][DMODEL] f32); Op is dead
  // before Wo-part writes Pp. Hb separate.
  float* Pp = (float*)alloc((size_t)2 * NTOK * DMODEL * 4);
  short* Hb = (short*)alloc((size_t)NTOK * DFF * 2);
  float* Op = Pp;  // alias
  float* x1f = (float*)alloc((size_t)NTOK * DMODEL * 4);
  short* x1b = (short*)alloc((size_t)NTOK * DMODEL * 2);

  // 1) all static prep (6 transposes + bias concat) in one dispatch
  prep_static<<<12300, dim3(32, 8), 0, stream>>>(
      Wq, Wk, Wv, Wo, W1, W2, bq, bk, bv, WqkvT, WoT, W1T, W2T, bqkv);

  // 2) token + corr prep in one dispatch
  prep_inputs<<<12288, 256, 0, stream>>>(src, pos, corr, qkb, srcb, corrb);

  // 3) fused Q|K|V projection: cols<2048 use qkb, cols>=2048 use srcb
  gemm_bt<0, 1><<<dim3(QKVLD / 128, NTOK / 128), 256, 0, stream>>>(
      qkb, srcb, WqkvT, bqkv, nullptr, QKVb, NTOK, QKVLD, DMODEL, 2048);

  // 4) V^T for attention PV a-operand (V = cols 2048.. of QKVb)
  transpose_bf16<<<dim3(DMODEL / 64, NTOK / 64), 256, 0, stream>>>(
      QKVb + 2048, VTt, NTOK, QKVLD);

  // 5) attention, split-K x2, 64 q-rows/block: grid (16,32,4) = 2048 blocks
  //    of 256 thr = 8 independent blocks/CU
  attn_kernel<<<dim3(NHEAD, S_LEN / 64, BATCH * NSPLIT), 256, 0, stream>>>(
      QKVb, VTt, corrb, Op, lp);
  combine_ctx<<<(NTOK * DMODEL) / (256 * 4), 256, 0, stream>>>(Op, lp, ctxb);

  // 6) output projection: split-K x2 partials, summed in LN1
  gemm_bt_part<<<dim3(DMODEL / 128, NTOK / 128, 2), 256, 0, stream>>>(
      ctxb, WoT, Pp, NTOK, DMODEL, DMODEL, DMODEL / 2);

  // 7) LN1: x1 = LN(src + P0 + P1 + bo)
  residual_ln3<<<NTOK, 256, 0, stream>>>(src, Pp, Pp + (size_t)NTOK * DMODEL,
                                         bo, g1, be1, x1f, x1b);

  // 8) FFN1 (128x128, 1024 blocks)
  gemm_bt<1, 1><<<dim3(DFF / 128, NTOK / 128), 256, 0, stream>>>(
      x1b, x1b, W1T, b1, nullptr, Hb, NTOK, DFF, DMODEL, 1 << 30);

  // 9) FFN2: split-K x2 partials, summed in LN2
  gemm_bt_part<<<dim3(DMODEL / 128, NTOK / 128, 2), 256, 0, stream>>>(
      Hb, W2T, Pp, NTOK, DMODEL, DFF, DFF / 2);

  // 10) LN2 -> output
  residual_ln3<<<NTOK, 256, 0, stream>>>(x1f, Pp, Pp + (size_t)NTOK * DMODEL,
                                         b2, g2, be2, out, nullptr);
}

// Round 10
// 449.398 us; speedup vs baseline: 1.9592x; 1.0641x over previous
//
#include <hip/hip_runtime.h>
#include <hip/hip_bf16.h>

#define S_LEN  2048
#define BATCH  2
#define DMODEL 1024
#define NHEAD  16
#define DHEAD  64
#define DFF    4096
#define NTOK   (BATCH * S_LEN)
#define QKVLD  3072   // fused Q|K|V output row stride
#define NSPLIT 2      // attention split-K factor

typedef __attribute__((ext_vector_type(8))) short short8;
typedef __attribute__((ext_vector_type(4))) short short4v;
typedef __attribute__((ext_vector_type(4))) float f32x4;

__device__ __forceinline__ short f2bs(float f) {
  __hip_bfloat16 h = __float2bfloat16(f);
  short s;
  __builtin_memcpy(&s, &h, sizeof(short));
  return s;
}

__device__ __forceinline__ float bs2f(short s) {
  unsigned u = ((unsigned)(unsigned short)s) << 16;
  float f;
  __builtin_memcpy(&f, &u, sizeof(float));
  return f;
}

__device__ __forceinline__ f32x4 mfma16(short8 a, short8 b, f32x4 c) {
  return __builtin_amdgcn_mfma_f32_16x16x32_bf16(a, b, c, 0, 0, 0);
}

// async global->LDS, 16B per lane; LDS dest = wave-uniform base + lane*16
__device__ __forceinline__ void load_lds16(const short* g, short* l) {
  __builtin_amdgcn_global_load_lds(
      (const __attribute__((address_space(1))) void*)g,
      (__attribute__((address_space(3))) void*)l, 16, 0, 0);
}

// ---------------------------------------------------------------------------
// prep_static: ALL weight transposes + bias concat in ONE dispatch.
// ---------------------------------------------------------------------------
__global__ void prep_static(
    const float* __restrict__ Wq, const float* __restrict__ Wk,
    const float* __restrict__ Wv, const float* __restrict__ Wo,
    const float* __restrict__ W1, const float* __restrict__ W2,
    const float* __restrict__ bq, const float* __restrict__ bk,
    const float* __restrict__ bv,
    short* __restrict__ WqkvT, short* __restrict__ WoT,
    short* __restrict__ W1T, short* __restrict__ W2T,
    float* __restrict__ bqkv) {
  const int gid = blockIdx.x;
  const int tx = threadIdx.x, ty = threadIdx.y;  // 32 x 8

  if (gid >= 12288) {  // bias concat
    const int i = (gid - 12288) * 256 + ty * 32 + tx;
    float v;
    if (i < DMODEL) v = bq[i] * 0.125f;
    else if (i < 2 * DMODEL) v = bk[i - DMODEL];
    else v = bv[i - 2 * DMODEL];
    bqkv[i] = v;
    return;
  }

  const float* in;
  short* out;
  int R, C, t;
  float scale = 1.0f;
  if (gid < 4096) {
    t = gid & 1023;
    R = C = 1024;
    if (gid < 1024)      { in = Wq; out = WqkvT;                 scale = 0.125f; }
    else if (gid < 2048) { in = Wk; out = WqkvT + 1024 * 1024; }
    else if (gid < 3072) { in = Wv; out = WqkvT + 2 * 1024 * 1024; }
    else                 { in = Wo; out = WoT; }
  } else if (gid < 8192) {
    t = gid - 4096; in = W1; out = W1T; R = 1024; C = 4096;
  } else {
    t = gid - 8192; in = W2; out = W2T; R = 4096; C = 1024;
  }
  const int tpr = C >> 5;  // tiles per row of C
  const int c0 = (t % tpr) * 32, r0 = (t / tpr) * 32;

  __shared__ float tile[32][33];
#pragma unroll
  for (int i = 0; i < 32; i += 8)
    tile[ty + i][tx] = in[(size_t)(r0 + ty + i) * C + c0 + tx];
  __syncthreads();
#pragma unroll
  for (int i = 0; i < 32; i += 8)
    out[(size_t)(c0 + ty + i) * R + r0 + tx] = f2bs(tile[tx][ty + i] * scale);
}

// ---------------------------------------------------------------------------
// prep_inputs: tokens (qkb/srcb) + corr->bf16 in ONE dispatch.
// ---------------------------------------------------------------------------
__global__ void prep_inputs(const float* __restrict__ src, const float* __restrict__ pos,
                            const float* __restrict__ corr,
                            short* __restrict__ qkb, short* __restrict__ srcb,
                            short* __restrict__ corrb) {
  const int gid = blockIdx.x;
  if (gid < 4096) {
    const int i = gid * 1024 + threadIdx.x * 4;
    float4 s = *(const float4*)(src + i);
    float4 p = *(const float4*)(pos + i);
    short4v q4 = {f2bs(s.x + p.x), f2bs(s.y + p.y), f2bs(s.z + p.z), f2bs(s.w + p.w)};
    short4v s4 = {f2bs(s.x), f2bs(s.y), f2bs(s.z), f2bs(s.w)};
    *(short4v*)(qkb + i) = q4;
    *(short4v*)(srcb + i) = s4;
  } else {
    const size_t i = ((size_t)(gid - 4096)) * 1024 + threadIdx.x * 4;
    float4 c = *(const float4*)(corr + i);
    short4v o = {f2bs(c.x), f2bs(c.y), f2bs(c.z), f2bs(c.w)};
    *(short4v*)(corrb + i) = o;
  }
}

// ---------------------------------------------------------------------------
// bf16 transpose: in [R][LDin] -> out [C][R], 64x64 tiles
// ---------------------------------------------------------------------------
__global__ __launch_bounds__(256) void transpose_bf16(
    const short* __restrict__ in, short* __restrict__ out, int R, int LDin) {
  __shared__ __attribute__((aligned(16))) short tile[64][72];
  const int c0 = blockIdx.x * 64, r0 = blockIdx.y * 64;
#pragma unroll
  for (int i = 0; i < 2; i++) {
    const int idx = threadIdx.x + 256 * i;
    const int rr = idx >> 3, cc8 = (idx & 7) * 8;
    *(int4*)(&tile[rr][cc8]) = *(const int4*)(in + (size_t)(r0 + rr) * LDin + c0 + cc8);
  }
  __syncthreads();
#pragma unroll
  for (int i = 0; i < 2; i++) {
    const int idx = threadIdx.x + 256 * i;
    const int rr = idx >> 3, cc8 = (idx & 7) * 8;
    short8 v;
#pragma unroll
    for (int j = 0; j < 8; j++) v[j] = tile[cc8 + j][rr];
    *(short8*)(out + (size_t)(c0 + rr) * R + r0 + cc8) = v;
  }
}

// ---------------------------------------------------------------------------
// R10: 256x256 deep-pipelined GEMM (8-phase-template derivative, T2+T3+T4+T5).
// BK=64, 2-buffer LDS (128 KB -> 1 block/CU), 512 thr = 8 waves (2Mx4N).
// Per wave: output 128x64 as 2x2 quadrants of (4 M-frags x 2 N-frags);
// 4 phases per K-tile, each: stage ONE half-tile (2 x global_load_lds,
// pre-swizzled source per rule 21) + swizzled ds_read_b128 frags + 16 MFMA
// between raw s_barriers. ONE counted vmcnt(4) per K-tile (never 0): 2
// half-tiles stay in flight across every barrier.
// Slot-free proof: A-half0(t) last read P2, A0h(t+2) staged P3; B-half0(t)
// last read P3, staged P4; A1h/B1h(t+1) staged P1/P2 into the other buffer.
// Residency proof: vmcnt(4) at t.P4 leaves only {A0h(t+2),B0h(t+2)} in
// flight -> everything iteration t+1 reads is complete + barrier-published.
// Tail: t+1/t+2 K-indices clamp to NT-1 (writes land in never-again-read
// slots; keeps vmcnt counts uniform).
// ---------------------------------------------------------------------------
template <int RELU>
__global__ __launch_bounds__(512, 2) void gemm_bt8(
    const short* __restrict__ A0, const short* __restrict__ A1,
    const short* __restrict__ Bt, const float* __restrict__ bias,
    short* __restrict__ Cb, int M, int N, int K, int splitcol) {
  __shared__ __attribute__((aligned(16))) short As[2][256 * 64];  // 2x32 KB
  __shared__ __attribute__((aligned(16))) short Bs[2][256 * 64];  // 2x32 KB

  const int tid = threadIdx.x;
  const int wave = tid >> 6, lane = tid & 63;
  const int lm = lane & 15, lq = lane >> 4;
  const int wm = wave >> 2, wn = wave & 3;  // 2 x 4 wave grid
  const int row0 = blockIdx.y * 256, col0 = blockIdx.x * 256;
  const short* A = (col0 < splitcol) ? A0 : A1;

  // staging: thread covers rows srow, srow+64 of a 128-row half, phys unit
  // tid&7 (16B units); logical (global) unit = phys ^ (row&7)  [rule 21]
  const int srow = tid >> 3;
  const int lu = ((tid & 7) ^ (srow & 7)) * 8;  // logical unit short offset

#define STG(DSTHALF, SRC, LD, TR, KT) do {                                     \
    const short* _s = (SRC) + (size_t)((TR) + srow) * (LD) +                   \
                      (size_t)(KT) * 64 + lu;                                  \
    load_lds16(_s, (DSTHALF) + wave * 512);                                    \
    load_lds16(_s + (size_t)64 * (LD), (DSTHALF) + 4096 + wave * 512);         \
  } while (0)

  // read-side swizzle: row&7 == lm&7 for all frag rows (offsets mult of 16)
  const int fk = lm & 7;
  const int u0 = (lq ^ fk) * 8, u1 = ((4 + lq) ^ fk) * 8;
  const int arow = (wm * 64 + lm) * 64;  // per-lane row base (shorts)
  const int brow = (wn * 32 + lm) * 64;

  f32x4 acc[2][4][2][2];
#pragma unroll
  for (int a = 0; a < 2; a++)
#pragma unroll
    for (int i = 0; i < 4; i++)
#pragma unroll
      for (int b = 0; b < 2; b++)
#pragma unroll
        for (int j = 0; j < 2; j++) acc[a][i][b][j] = (f32x4){0.f, 0.f, 0.f, 0.f};

  short8 af[4][2], bf0[2][2], bf1[2][2];

  const int NT = K >> 6;
  // prologue: A0h(0) B0h(0) A1h(0) B1h(0) A0h(1) B0h(1) = 12 loads
  STG(&As[0][0],    A,  K, row0,       0);
  STG(&Bs[0][0],    Bt, K, col0,       0);
  STG(&As[0][8192], A,  K, row0 + 128, 0);
  STG(&Bs[0][8192], Bt, K, col0 + 128, 0);
  STG(&As[1][0],    A,  K, row0,       1);
  STG(&Bs[1][0],    Bt, K, col0,       1);
  asm volatile("s_waitcnt vmcnt(4)" ::: "memory");  // tile 0 resident
  __builtin_amdgcn_s_barrier();

  for (int t = 0; t < NT; ++t) {
    const int cur = t & 1, nxt = cur ^ 1;
    const int t1 = (t + 1 < NT) ? t + 1 : NT - 1;
    const int t2 = (t + 2 < NT) ? t + 2 : NT - 1;
    const short* Ac = As[cur];
    const short* Bc = Bs[cur];

    // ---- P1: stage A1h(t+1); read A-half0 + B-half0; MFMA quadrant (0,0)
    STG(&As[nxt][8192], A, K, row0 + 128, t1);
#pragma unroll
    for (int i = 0; i < 4; i++) {
      af[i][0] = *(const short8*)(&Ac[arow + i * 1024 + u0]);
      af[i][1] = *(const short8*)(&Ac[arow + i * 1024 + u1]);
    }
#pragma unroll
    for (int j = 0; j < 2; j++) {
      bf0[j][0] = *(const short8*)(&Bc[brow + j * 1024 + u0]);
      bf0[j][1] = *(const short8*)(&Bc[brow + j * 1024 + u1]);
    }
    __builtin_amdgcn_s_setprio(1);
#pragma unroll
    for (int i = 0; i < 4; i++)
#pragma unroll
      for (int j = 0; j < 2; j++) {
        acc[0][i][0][j] = mfma16(af[i][0], bf0[j][0], acc[0][i][0][j]);
        acc[0][i][0][j] = mfma16(af[i][1], bf0[j][1], acc[0][i][0][j]);
      }
    __builtin_amdgcn_s_setprio(0);
    __builtin_amdgcn_s_barrier();

    // ---- P2: stage B1h(t+1); read B-half1; MFMA quadrant (0,1)
    STG(&Bs[nxt][8192], Bt, K, col0 + 128, t1);
#pragma unroll
    for (int j = 0; j < 2; j++) {
      bf1[j][0] = *(const short8*)(&Bc[8192 + brow + j * 1024 + u0]);
      bf1[j][1] = *(const short8*)(&Bc[8192 + brow + j * 1024 + u1]);
    }
    __builtin_amdgcn_s_setprio(1);
#pragma unroll
    for (int i = 0; i < 4; i++)
#pragma unroll
      for (int j = 0; j < 2; j++) {
        acc[0][i][1][j] = mfma16(af[i][0], bf1[j][0], acc[0][i][1][j]);
        acc[0][i][1][j] = mfma16(af[i][1], bf1[j][1], acc[0][i][1][j]);
      }
    __builtin_amdgcn_s_setprio(0);
    __builtin_amdgcn_s_barrier();

    // ---- P3: stage A0h(t+2) (slot free since P2); read A-half1; MFMA (1,0)
    STG(&As[cur][0], A, K, row0, t2);
#pragma unroll
    for (int i = 0; i < 4; i++) {
      af[i][0] = *(const short8*)(&Ac[8192 + arow + i * 1024 + u0]);
      af[i][1] = *(const short8*)(&Ac[8192 + arow + i * 1024 + u1]);
    }
    __builtin_amdgcn_s_setprio(1);
#pragma unroll
    for (int i = 0; i < 4; i++)
#pragma unroll
      for (int j = 0; j < 2; j++) {
        acc[1][i][0][j] = mfma16(af[i][0], bf0[j][0], acc[1][i][0][j]);
        acc[1][i][0][j] = mfma16(af[i][1], bf0[j][1], acc[1][i][0][j]);
      }
    __builtin_amdgcn_s_setprio(0);
    __builtin_amdgcn_s_barrier();

    // ---- P4: stage B0h(t+2) (slot free since P3); MFMA (1,1); vmcnt(4)
    STG(&Bs[cur][0], Bt, K, col0, t2);
    __builtin_amdgcn_s_setprio(1);
#pragma unroll
    for (int i = 0; i < 4; i++)
#pragma unroll
      for (int j = 0; j < 2; j++) {
        acc[1][i][1][j] = mfma16(af[i][0], bf1[j][0], acc[1][i][1][j]);
        acc[1][i][1][j] = mfma16(af[i][1], bf1[j][1], acc[1][i][1][j]);
      }
    __builtin_amdgcn_s_setprio(0);
    asm volatile("s_waitcnt vmcnt(4)" ::: "memory");  // leave only P3/P4 stages
    __builtin_amdgcn_s_barrier();
  }
#undef STG

  // ---- epilogue: bias (+ReLU) + bf16 store (same mapping as proven gemm_bt)
#pragma unroll
  for (int a = 0; a < 2; a++)
#pragma unroll
    for (int i = 0; i < 4; i++)
#pragma unroll
      for (int b = 0; b < 2; b++)
#pragma unroll
        for (int j = 0; j < 2; j++) {
          const int col = col0 + b * 128 + wn * 32 + j * 16 + lm;
          const float bsv = bias[col];
#pragma unroll
          for (int r = 0; r < 4; r++) {
            const int row = row0 + a * 128 + wm * 64 + i * 16 + lq * 4 + r;
            float v = acc[a][i][b][j][r] + bsv;
            if (RELU) v = fmaxf(v, 0.f);
            Cb[(size_t)row * N + col] = f2bs(v);
          }
        }
}

// ---------------------------------------------------------------------------
// Split-K GEMM 128x128: block z covers K range [z*Kslice, (z+1)*Kslice),
// writes f32 partial (no bias) to Cf + z*M*N. No atomics.
// ---------------------------------------------------------------------------
__global__ __launch_bounds__(256) void gemm_bt_part(
    const short* __restrict__ A, const short* __restrict__ Bt,
    float* __restrict__ Cf, int M, int N, int K, int Kslice) {
  __shared__ __attribute__((aligned(16))) short As[128 * 32];
  __shared__ __attribute__((aligned(16))) short Bs[128 * 32];

  const int tid = threadIdx.x;
  const int wave = tid >> 6, lane = tid & 63;
  const int lm = lane & 15, lq = lane >> 4;
  const int row0 = blockIdx.y * 128, col0 = blockIdx.x * 128;
  const int kbase = blockIdx.z * Kslice;
  const int wr = (wave >> 1) * 64, wc = (wave & 1) * 64;
  Cf += (size_t)blockIdx.z * M * N;

  const short* ag = A + (size_t)(row0 + wave * 32 + (lane >> 2)) * K + (lane & 3) * 8;
  const short* bg = Bt + (size_t)(col0 + wave * 32 + (lane >> 2)) * K + (lane & 3) * 8;
  short* asl = &As[wave * 32 * 32];
  short* bsl = &Bs[wave * 32 * 32];

  f32x4 acc[4][4];
#pragma unroll
  for (int i = 0; i < 4; i++)
#pragma unroll
    for (int j = 0; j < 4; j++) acc[i][j] = (f32x4){0.f, 0.f, 0.f, 0.f};

  for (int k0 = kbase; k0 < kbase + Kslice; k0 += 32) {
    load_lds16(ag + k0, asl);
    load_lds16(ag + (size_t)16 * K + k0, asl + 16 * 32);
    load_lds16(bg + k0, bsl);
    load_lds16(bg + (size_t)16 * K + k0, bsl + 16 * 32);
    __syncthreads();

    short8 af[4], bfr[4];
#pragma unroll
    for (int i = 0; i < 4; i++)
      af[i] = *(const short8*)(&As[(wr + 16 * i + lm) * 32 + lq * 8]);
#pragma unroll
    for (int j = 0; j < 4; j++)
      bfr[j] = *(const short8*)(&Bs[(wc + 16 * j + lm) * 32 + lq * 8]);
#pragma unroll
    for (int i = 0; i < 4; i++)
#pragma unroll
      for (int j = 0; j < 4; j++) acc[i][j] = mfma16(af[i], bfr[j], acc[i][j]);
    __syncthreads();
  }

#pragma unroll
  for (int i = 0; i < 4; i++) {
#pragma unroll
    for (int j = 0; j < 4; j++) {
      const int col = col0 + wc + 16 * j + lm;
#pragma unroll
      for (int r = 0; r < 4; r++) {
        const int row = row0 + wr + 16 * i + lq * 4 + r;
        Cf[(size_t)row * N + col] = acc[i][j][r];
      }
    }
  }
}

// ---------------------------------------------------------------------------
// Fused attention (R7 config — best measured: 94.4 us). S^T form, split-K
// x2, KVBLK=32, 512 thr = 8 waves x 16 q-rows, wave-specialized staging
// (waves 0-3 K, 4-7 V), 16 KB LDS, 32+32 VGPR (fits 8-waves/EU budget).
// Occupancy study closed: 2 blk/CU=114us, 4=94us, 8=100us -> 4 is optimal.
// ---------------------------------------------------------------------------
__global__ __launch_bounds__(512, 8) void attn_kernel(
    const short* __restrict__ QKV,   // [NTOK][3072]: Q*0.125 | K | V
    const short* __restrict__ VT,    // [DMODEL][NTOK]
    const short* __restrict__ corrb, // [B][S][S] bf16
    float* __restrict__ Op,          // [NSPLIT][NTOK][DMODEL] partial numerators
    float* __restrict__ lp) {        // [NSPLIT][NTOK][NHEAD] partial denominators
  const int h = blockIdx.x, qtile = blockIdx.y;
  const int b = blockIdx.z >> 1, split = blockIdx.z & 1;
  const int koff = split * (S_LEN / NSPLIT);
  const int tid = threadIdx.x;
  const int wave = tid >> 6, lane = tid & 63;
  const int lm = lane & 15, lq = lane >> 4;
  const int qb = qtile * 128 + wave * 16;
  const int fx = lm & 7;         // K-tile read swizzle key (8 units/row)
  const int fy = (lm >> 1) & 3;  // V/P read swizzle key (4 units/row)

  __shared__ __attribute__((aligned(16))) short Ks[32 * 64];      // 4 KB
  __shared__ __attribute__((aligned(16))) short Vs[64 * 32];      // 4 KB
  __shared__ __attribute__((aligned(16))) short Ps[8 * 16 * 32];  // 8 KB

  const short* q0 = QKV + (size_t)(b * S_LEN + qb + lm) * QKVLD + h * DHEAD;
  const short8 qA0 = *(const short8*)(q0 + lq * 8);
  const short8 qA1 = *(const short8*)(q0 + lq * 8 + 32);

  f32x4 oA[4];
#pragma unroll
  for (int t = 0; t < 4; t++) oA[t] = (f32x4){0.f, 0.f, 0.f, 0.f};
  f32x4 lacc = (f32x4){0.f, 0.f, 0.f, 0.f};

  const short* c0 = corrb + (size_t)(b * S_LEN + qb + lm) * S_LEN;

  const int st = tid & 255;
  const bool isK = tid < 256;
  short* sdst;
  const short* sgp;
  size_t sstep;
  if (isK) {
    const int krow = st >> 3, ku = st & 7;
    sdst = &Ks[krow * 64 + ((ku ^ (krow & 7)) * 8)];
    sgp = QKV + (size_t)(b * S_LEN + koff + krow) * QKVLD + DMODEL + h * DHEAD + ku * 8;
    sstep = (size_t)32 * QKVLD;
  } else {
    const int vrow = st >> 2, vu = st & 3;
    sdst = &Vs[vrow * 32 + ((vu ^ ((vrow >> 1) & 3)) * 8)];
    sgp = VT + (size_t)(h * DHEAD + vrow) * NTOK + b * S_LEN + koff + vu * 8;
    sstep = 32;
  }

  for (int kt = koff; kt < koff + S_LEN / NSPLIT; kt += 32) {
    *(int4*)sdst = *(const int4*)sgp;
    sgp += sstep;
    __syncthreads();

    f32x4 sv[2];
    __builtin_amdgcn_s_setprio(1);
#pragma unroll
    for (int t = 0; t < 2; t++) {
      const int rb = (t * 16 + lm) * 64;
      const short8 kf0 = *(const short8*)(&Ks[rb + (lq ^ fx) * 8]);
      const short8 kf1 = *(const short8*)(&Ks[rb + ((lq + 4) ^ fx) * 8]);
      f32x4 a = (f32x4){0.f, 0.f, 0.f, 0.f};
      a = mfma16(kf0, qA0, a);
      a = mfma16(kf1, qA1, a);
      sv[t] = a;
    }
    __builtin_amdgcn_s_setprio(0);

#pragma unroll
    for (int t = 0; t < 2; t++) {
      const short4v cr = *(const short4v*)(c0 + kt + t * 16 + lq * 4);
#pragma unroll
      for (int r = 0; r < 4; r++)
        sv[t][r] = __expf(sv[t][r] + bs2f(cr[r]));
      lacc += sv[t];
      short4v pA = {f2bs(sv[t][0]), f2bs(sv[t][1]), f2bs(sv[t][2]), f2bs(sv[t][3])};
      const int pu = ((2 * t + (lq >> 1)) ^ fy) * 8 + (lq & 1) * 4;
      *(short4v*)(&Ps[wave * 512 + lm * 32 + pu]) = pA;
    }

    const short8 pA0 = *(const short8*)(&Ps[wave * 512 + lm * 32 + (lq ^ fy) * 8]);
    __builtin_amdgcn_s_setprio(1);
#pragma unroll
    for (int t = 0; t < 4; t++) {
      const int vrb = (t * 16 + lm) * 32;
      const short8 vf0 = *(const short8*)(&Vs[vrb + (lq ^ fy) * 8]);
      oA[t] = mfma16(vf0, pA0, oA[t]);
    }
    __builtin_amdgcn_s_setprio(0);
    __syncthreads();
  }

  float lA = lacc[0] + lacc[1] + lacc[2] + lacc[3];
  lA += __shfl_xor(lA, 16);
  lA += __shfl_xor(lA, 32);
  if (lq == 0)
    lp[((size_t)split * NTOK + b * S_LEN + qb + lm) * NHEAD + h] = lA;
  float* opA = Op + (size_t)split * NTOK * DMODEL +
               (size_t)(b * S_LEN + qb + lm) * DMODEL + h * DHEAD;
#pragma unroll
  for (int t = 0; t < 4; t++)
    *(f32x4*)(opA + t * 16 + lq * 4) = oA[t];
}

// ---------------------------------------------------------------------------
// Combine split-K partials: ctx = (O0+O1)/(l0+l1), bf16
// ---------------------------------------------------------------------------
__global__ __launch_bounds__(256) void combine_ctx(
    const float* __restrict__ Op, const float* __restrict__ lp,
    short* __restrict__ ctx) {
  const size_t idx = ((size_t)blockIdx.x * 256 + threadIdx.x) * 4;
  const int token = (int)(idx >> 10);
  const int d = (int)(idx & 1023);
  const int h = d >> 6;
  f32x4 o = (f32x4){0.f, 0.f, 0.f, 0.f};
  float l = 0.f;
#pragma unroll
  for (int s = 0; s < NSPLIT; s++) {
    o += *(const f32x4*)(Op + (size_t)s * NTOK * DMODEL + idx);
    l += lp[((size_t)s * NTOK + token) * NHEAD + h];
  }
  const float inv = 1.0f / l;
  short4v ov = {f2bs(o[0] * inv), f2bs(o[1] * inv),
                f2bs(o[2] * inv), f2bs(o[3] * inv)};
  *(short4v*)(ctx + idx) = ov;
}

// ---------------------------------------------------------------------------
// Residual + 2 GEMM partials + bias + LayerNorm. One block per token row.
// ---------------------------------------------------------------------------
__global__ __launch_bounds__(256) void residual_ln3(
    const float* __restrict__ xa, const float* __restrict__ p0,
    const float* __restrict__ p1, const float* __restrict__ bias,
    const float* __restrict__ g, const float* __restrict__ be,
    float* __restrict__ outf, short* __restrict__ outb) {
  const int row = blockIdx.x;
  const int t = threadIdx.x;
  const size_t base = (size_t)row * DMODEL + t * 4;
  float4 a = *(const float4*)(xa + base);
  f32x4 q0 = *(const f32x4*)(p0 + base);
  f32x4 q1 = *(const f32x4*)(p1 + base);
  f32x4 bb = *(const f32x4*)(bias + t * 4);
  const float v0 = a.x + q0[0] + q1[0] + bb[0];
  const float v1 = a.y + q0[1] + q1[1] + bb[1];
  const float v2 = a.z + q0[2] + q1[2] + bb[2];
  const float v3 = a.w + q0[3] + q1[3] + bb[3];
  float sum = v0 + v1 + v2 + v3;
  float sq = v0 * v0 + v1 * v1 + v2 * v2 + v3 * v3;
#pragma unroll
  for (int off = 1; off < 64; off <<= 1) {
    sum += __shfl_xor(sum, off);
    sq += __shfl_xor(sq, off);
  }
  __shared__ float ssum[4], ssq[4];
  const int wave = t >> 6;
  if ((t & 63) == 0) { ssum[wave] = sum; ssq[wave] = sq; }
  __syncthreads();
  sum = ssum[0] + ssum[1] + ssum[2] + ssum[3];
  sq = ssq[0] + ssq[1] + ssq[2] + ssq[3];
  const float mean = sum * (1.0f / DMODEL);
  const float var = sq * (1.0f / DMODEL) - mean * mean;
  const float rstd = rsqrtf(var + 1e-5f);
  float4 gv = *(const float4*)(g + t * 4);
  float4 bv = *(const float4*)(be + t * 4);
  const float o0 = (v0 - mean) * rstd * gv.x + bv.x;
  const float o1 = (v1 - mean) * rstd * gv.y + bv.y;
  const float o2 = (v2 - mean) * rstd * gv.z + bv.z;
  const float o3 = (v3 - mean) * rstd * gv.w + bv.w;
  if (outf) {
    float4 ov = {o0, o1, o2, o3};
    *(float4*)(outf + base) = ov;
  }
  if (outb) {
    short4v ob = {f2bs(o0), f2bs(o1), f2bs(o2), f2bs(o3)};
    *(short4v*)(outb + base) = ob;
  }
}

// ---------------------------------------------------------------------------
extern "C" void kernel_launch(void* const* d_in, const int* in_sizes, int n_in,
                              void* d_out, int out_size, void* d_ws, size_t ws_size,
                              hipStream_t stream) {
  const float* src = (const float*)d_in[0];
  const float* corr = (const float*)d_in[1];
  const float* pos = (const float*)d_in[2];
  const float* Wq = (const float*)d_in[3];
  const float* bq = (const float*)d_in[4];
  const float* Wk = (const float*)d_in[5];
  const float* bk = (const float*)d_in[6];
  const float* Wv = (const float*)d_in[7];
  const float* bv = (const float*)d_in[8];
  const float* Wo = (const float*)d_in[9];
  const float* bo = (const float*)d_in[10];
  const float* W1 = (const float*)d_in[11];
  const float* b1 = (const float*)d_in[12];
  const float* W2 = (const float*)d_in[13];
  const float* b2 = (const float*)d_in[14];
  const float* g1 = (const float*)d_in[15];
  const float* be1 = (const float*)d_in[16];
  const float* g2 = (const float*)d_in[17];
  const float* be2 = (const float*)d_in[18];
  float* out = (float*)d_out;

  char* ws = (char*)d_ws;
  size_t off = 0;
  auto alloc = [&](size_t bytes) {
    char* p = ws + off;
    off += (bytes + 255) & ~(size_t)255;
    return p;
  };
  short* WqkvT = (short*)alloc((size_t)QKVLD * DMODEL * 2);  // [3072][1024]
  short* WoT = (short*)alloc((size_t)DMODEL * DMODEL * 2);
  short* W1T = (short*)alloc((size_t)DFF * DMODEL * 2);
  short* W2T = (short*)alloc((size_t)DMODEL * DFF * 2);
  float* bqkv = (float*)alloc((size_t)QKVLD * 4);
  short* qkb = (short*)alloc((size_t)NTOK * DMODEL * 2);
  short* srcb = (short*)alloc((size_t)NTOK * DMODEL * 2);
  short* QKVb = (short*)alloc((size_t)NTOK * QKVLD * 2);   // fused Q|K|V (24 MB)
  short* VTt = (short*)alloc((size_t)DMODEL * NTOK * 2);
  short* corrb = (short*)alloc((size_t)BATCH * S_LEN * S_LEN * 2);  // 16.8 MB
  short* ctxb = (short*)alloc((size_t)NTOK * DMODEL * 2);
  float* lp = (float*)alloc((size_t)NSPLIT * NTOK * NHEAD * 4);
  // Pp (33.55 MB) aliased by attn's Op ([2][NTOK][DMODEL] f32); Op is dead
  // before Wo-part writes Pp. Hb separate.
  float* Pp = (float*)alloc((size_t)2 * NTOK * DMODEL * 4);
  short* Hb = (short*)alloc((size_t)NTOK * DFF * 2);
  float* Op = Pp;  // alias
  float* x1f = (float*)alloc((size_t)NTOK * DMODEL * 4);
  short* x1b = (short*)alloc((size_t)NTOK * DMODEL * 2);

  // 1) all static prep (6 transposes + bias concat) in one dispatch
  prep_static<<<12300, dim3(32, 8), 0, stream>>>(
      Wq, Wk, Wv, Wo, W1, W2, bq, bk, bv, WqkvT, WoT, W1T, W2T, bqkv);

  // 2) token + corr prep in one dispatch
  prep_inputs<<<12288, 256, 0, stream>>>(src, pos, corr, qkb, srcb, corrb);

  // 3) fused Q|K|V projection (8-phase 256x256): cols<2048 qkb, >=2048 srcb
  gemm_bt8<0><<<dim3(QKVLD / 256, NTOK / 256), 512, 0, stream>>>(
      qkb, srcb, WqkvT, bqkv, QKVb, NTOK, QKVLD, DMODEL, 2048);

  // 4) V^T for attention PV a-operand (V = cols 2048.. of QKVb)
  transpose_bf16<<<dim3(DMODEL / 64, NTOK / 64), 256, 0, stream>>>(
      QKVb + 2048, VTt, NTOK, QKVLD);

  // 5) attention (R7 config) + combine
  attn_kernel<<<dim3(NHEAD, S_LEN / 128, BATCH * NSPLIT), 512, 0, stream>>>(
      QKVb, VTt, corrb, Op, lp);
  combine_ctx<<<(NTOK * DMODEL) / (256 * 4), 256, 0, stream>>>(Op, lp, ctxb);

  // 6) output projection: split-K x2 partials, summed in LN1
  gemm_bt_part<<<dim3(DMODEL / 128, NTOK / 128, 2), 256, 0, stream>>>(
      ctxb, WoT, Pp, NTOK, DMODEL, DMODEL, DMODEL / 2);

  // 7) LN1: x1 = LN(src + P0 + P1 + bo)
  residual_ln3<<<NTOK, 256, 0, stream>>>(src, Pp, Pp + (size_t)NTOK * DMODEL,
                                         bo, g1, be1, x1f, x1b);

  // 8) FFN1 (8-phase 256x256, 256 blocks, ReLU)
  gemm_bt8<1><<<dim3(DFF / 256, NTOK / 256), 512, 0, stream>>>(
      x1b, x1b, W1T, b1, Hb, NTOK, DFF, DMODEL, 1 << 30);

  // 9) FFN2: split-K x2 partials, summed in LN2
  gemm_bt_part<<<dim3(DMODEL / 128, NTOK / 128, 2), 256, 0, stream>>>(
      Hb, W2T, Pp, NTOK, DMODEL, DFF, DFF / 2);

  // 10) LN2 -> output
  residual_ln3<<<NTOK, 256, 0, stream>>>(x1f, Pp, Pp + (size_t)NTOK * DMODEL,
                                         b2, g2, be2, out, nullptr);
}